// Round 2
// baseline (591.785 us; speedup 1.0000x reference)
//
#include <hip/hip_runtime.h>
#include <cstdint>
#include <cstddef>

#define T_DATA 20000
#define E_NO 2000
#define I_NO 500
#define SUB_NO 16
#define HID 256
#define T_SYN 200
#define T_ENC 80
#define W_IN 159   // 2*T_ENC-1

typedef __attribute__((ext_vector_type(8))) __bf16 bf16x8;
typedef __attribute__((ext_vector_type(8))) short short8;
typedef __attribute__((ext_vector_type(4))) float floatx4;

__device__ __forceinline__ float bf2f(unsigned short u) {
    union { unsigned int i; float f; } v; v.i = ((unsigned int)u) << 16; return v.f;
}
__device__ __forceinline__ unsigned short f2bf(float f) {
    union { float f; unsigned int i; } v; v.f = f;
    unsigned int r = v.i + 0x7FFFu + ((v.i >> 16) & 1u);
    return (unsigned short)(r >> 16);
}
// dtype-agnostic scalar input load: isbf ? bf16[i] : f32[i]
__device__ __forceinline__ float inload(const void* p, int i, int isbf) {
    return isbf ? bf2f(((const unsigned short*)p)[i]) : ((const float*)p)[i];
}

// ---------------- ws layout (bytes, all 16B aligned) ----------------
#define OFF_FLAG   0u
#define OFF_KERE   16u        // 16*200 f32
#define OFF_KERI   12816u
#define OFF_ASSE   25616u     // 2000 i32
#define OFF_ASSI   33616u     // 500 i32
#define OFF_W1H    35616u     // 256*160 bf16
#define OFF_W1L    117536u
#define OFF_W2H    199456u    // 256*256 bf16
#define OFF_W2L    330528u
#define OFF_W3H    461600u
#define OFF_W3L    592672u
#define OFF_W4H    723744u    // 15*256 bf16
#define OFF_W4L    731424u
#define OFF_INE    739104u    // 20000*16 u8
#define OFF_INI    1059104u
#define OFF_SCONV  1379104u   // 20000*16 f32 ; total 2659104 bytes

// ============ kernel 0: dtype detector ============
// f32 spikes are words 0x00000000 / 0x3F800000 -> low16 always zero.
// bf16 spike pairs put 0x3F80 in low16 ~2% of words. 4096 words -> P(miss)~e^-82.
__global__ void k_detect(const unsigned int* Se_w, int* flag) {
    __shared__ int any;
    if (threadIdx.x == 0) any = 0;
    __syncthreads();
    int la = 0;
    for (int i = threadIdx.x; i < 4096; i += 256)
        if (Se_w[i] & 0xFFFFu) la = 1;
    if (la) atomicOr(&any, 1);
    __syncthreads();
    if (threadIdx.x == 0) flag[0] = any;
}

// ================= kernel 1: setup (kernels, assignments, weight repack) =================
__global__ void k_setup(const void* Ksyn, const void* tau_syn, const void* dly,
                        const void* Ce, const void* Ci,
                        const void* W1, const void* W2, const void* W3, const void* W4,
                        const int* flag, float* ker_e, float* ker_i, int* ass_e, int* ass_i,
                        unsigned short* W1h, unsigned short* W1l,
                        unsigned short* W2h, unsigned short* W2l,
                        unsigned short* W3h, unsigned short* W3l,
                        unsigned short* W4h, unsigned short* W4l) {
    int f = flag[0];
    int id = blockIdx.x * 256 + threadIdx.x;
    if (id < 6400) {
        int c = id < 3200 ? 0 : 1;
        int q = id - c * 3200;
        int s = q / 200, j = q - s * 200;
        float d = expf(inload(dly, s * 2 + c, f));
        float tt = fmaxf((float)j - d, 0.0f);
        float acc = 0.f;
        #pragma unroll
        for (int b = 0; b < 3; b++) {
            float tau = expf(inload(tau_syn, b * 3 + c, f));
            float x = tt / tau;
            acc += x * expf(-x) * inload(Ksyn, (s * 3 + b) * 3 + c, f);
        }
        (c == 0 ? ker_e : ker_i)[s * 200 + j] = acc;
    } else if (id < 8400) {
        int e = id - 6400;
        int a = 0;
        for (int s = 0; s < 16; s++) if (inload(Ce, s * E_NO + e, f) > 0.5f) a = s;
        ass_e[e] = a;
    } else if (id < 8900) {
        int e = id - 8400;
        int a = 0;
        for (int s = 0; s < 16; s++) if (inload(Ci, s * I_NO + e, f) > 0.5f) a = s;
        ass_i[e] = a;
    } else if (id < 49860) {          // W1 pad 159->160 + hi/lo split
        int q = id - 8900;
        int n = q / 160, k = q - n * 160;
        float v = (k < W_IN) ? inload(W1, n * W_IN + k, f) : 0.f;
        unsigned short hi = f2bf(v);
        W1h[q] = hi;
        W1l[q] = f2bf(v - bf2f(hi));
    } else if (id < 115396) {         // W2 hi/lo
        int q = id - 49860;
        float v = inload(W2, q, f);
        unsigned short hi = f2bf(v);
        W2h[q] = hi;
        W2l[q] = f2bf(v - bf2f(hi));
    } else if (id < 180932) {         // W3 hi/lo
        int q = id - 115396;
        float v = inload(W3, q, f);
        unsigned short hi = f2bf(v);
        W3h[q] = hi;
        W3l[q] = f2bf(v - bf2f(hi));
    } else if (id < 184772) {         // W4 hi/lo
        int q = id - 180932;
        float v = inload(W4, q, f);
        unsigned short hi = f2bf(v);
        W4h[q] = hi;
        W4l[q] = f2bf(v - bf2f(hi));
    }
}

// ============ kernel 2: spike -> subunit counts (u8) ============
__global__ void k_spikes(const void* Se, const void* Si,
                         const int* ass_e, const int* ass_i, const int* flag,
                         unsigned char* in_e, unsigned char* in_i) {
    int f = flag[0];
    int lane = threadIdx.x & 63;
    int wave = threadIdx.x >> 6;
    int t = blockIdx.x * 4 + wave;
    unsigned long long e0 = 0, e1 = 0, i0 = 0, i1 = 0;
    if (f) {  // bf16: 2 elements per u32 word
        const unsigned int* re = (const unsigned int*)((const unsigned short*)Se + (size_t)t * E_NO);
        #pragma unroll
        for (int it = 0; it < 16; it++) {
            int idx = it * 64 + lane;
            if (idx < E_NO / 2) {
                unsigned int v = re[idx];
                if (v & 0xFFFFu) {
                    int s = ass_e[idx * 2];
                    unsigned long long inc = 1ull << ((s & 7) * 8);
                    if (s < 8) e0 += inc; else e1 += inc;
                }
                if (v >> 16) {
                    int s = ass_e[idx * 2 + 1];
                    unsigned long long inc = 1ull << ((s & 7) * 8);
                    if (s < 8) e0 += inc; else e1 += inc;
                }
            }
        }
        const unsigned int* ri = (const unsigned int*)((const unsigned short*)Si + (size_t)t * I_NO);
        #pragma unroll
        for (int it = 0; it < 4; it++) {
            int idx = it * 64 + lane;
            if (idx < I_NO / 2) {
                unsigned int v = ri[idx];
                if (v & 0xFFFFu) {
                    int s = ass_i[idx * 2];
                    unsigned long long inc = 1ull << ((s & 7) * 8);
                    if (s < 8) i0 += inc; else i1 += inc;
                }
                if (v >> 16) {
                    int s = ass_i[idx * 2 + 1];
                    unsigned long long inc = 1ull << ((s & 7) * 8);
                    if (s < 8) i0 += inc; else i1 += inc;
                }
            }
        }
    } else {  // f32: 1 element per u32 word (0x0 or 0x3F800000)
        const unsigned int* re = (const unsigned int*)((const float*)Se + (size_t)t * E_NO);
        #pragma unroll
        for (int it = 0; it < 32; it++) {
            int idx = it * 64 + lane;
            if (idx < E_NO && re[idx]) {
                int s = ass_e[idx];
                unsigned long long inc = 1ull << ((s & 7) * 8);
                if (s < 8) e0 += inc; else e1 += inc;
            }
        }
        const unsigned int* ri = (const unsigned int*)((const float*)Si + (size_t)t * I_NO);
        #pragma unroll
        for (int it = 0; it < 8; it++) {
            int idx = it * 64 + lane;
            if (idx < I_NO && ri[idx]) {
                int s = ass_i[idx];
                unsigned long long inc = 1ull << ((s & 7) * 8);
                if (s < 8) i0 += inc; else i1 += inc;
            }
        }
    }
    for (int off = 32; off; off >>= 1) {
        e0 += __shfl_xor(e0, off);
        e1 += __shfl_xor(e1, off);
        i0 += __shfl_xor(i0, off);
        i1 += __shfl_xor(i1, off);
    }
    if (lane < 16) {
        unsigned long long a = (lane < 8) ? e0 : e1;
        in_e[(size_t)t * 16 + lane] = (unsigned char)((a >> ((lane & 7) * 8)) & 0xFF);
    } else if (lane < 32) {
        int s = lane - 16;
        unsigned long long a = (s < 8) ? i0 : i1;
        in_i[(size_t)t * 16 + s] = (unsigned char)((a >> ((s & 7) * 8)) & 0xFF);
    }
}

// ============ kernel 3: causal conv -> S_conv[T][16] f32 ============
__global__ void k_conv(const unsigned char* in_e, const unsigned char* in_i,
                       const float* ker_e, const float* ker_i, float* S_conv) {
    __shared__ float se[263 * 16];
    __shared__ float si[263 * 16];
    __shared__ float ke[16 * 201];
    __shared__ float ki[16 * 201];
    int t0 = blockIdx.x * 64;
    for (int idx = threadIdx.x; idx < 263 * 16; idx += 256) {
        int r = idx >> 4, s = idx & 15;
        int t = t0 - 199 + r;
        float ve = 0.f, vi = 0.f;
        if (t >= 0 && t < T_DATA) {
            ve = (float)in_e[(size_t)t * 16 + s];
            vi = (float)in_i[(size_t)t * 16 + s];
        }
        se[idx] = ve; si[idx] = vi;
    }
    for (int idx = threadIdx.x; idx < 3200; idx += 256) {
        int s = idx / 200, j = idx - s * 200;
        ke[s * 201 + j] = ker_e[idx];
        ki[s * 201 + j] = ker_i[idx];
    }
    __syncthreads();
    #pragma unroll
    for (int p = 0; p < 4; p++) {
        int idx = p * 256 + threadIdx.x;
        int tl = idx >> 4, s = idx & 15;
        int t = t0 + tl;
        if (t < T_DATA) {
            float acc = 0.f;
            #pragma unroll 4
            for (int j = 0; j < 200; j++) {
                int r = (tl + 199 - j) * 16 + s;
                acc += se[r] * ke[s * 201 + j];
                acc += si[r] * ki[s * 201 + j];
            }
            S_conv[(size_t)t * 16 + s] = acc;
        }
    }
}

// ============ kernel 4: fused sliding-window MLP + epilogue ============
// 64 t/block, 4 waves, each wave owns a 16-row strip (no inter-layer barriers).
// A and B both carried as hi+lo bf16 pairs; 3 MFMAs (ah*bh + al*bh + ah*bl)
// gives ~fp32 accuracy for the f32-input case; in the bf16 case lo==0 exactly.
__global__ void __launch_bounds__(256) k_mlp(
    const void* V, const int* flag,
    const unsigned short* W1h, const unsigned short* W1l, const void* b1, const void* a1p,
    const unsigned short* W2h, const unsigned short* W2l, const void* b2, const void* a2p,
    const unsigned short* W3h, const unsigned short* W3l, const void* b3, const void* a3p,
    const unsigned short* W4h, const unsigned short* W4l, const void* b4,
    const void* encb, const float* S_conv, void* out) {
    __shared__ __align__(16) unsigned short Ahi[64 * 256];
    __shared__ __align__(16) unsigned short Alo[64 * 256];
    int fl = flag[0];
    int tid = threadIdx.x;
    int lane = tid & 63, wave = tid >> 6;
    int lm = lane & 15, quad = lane >> 4;
    int t0 = blockIdx.x * 64;
    int mbase = wave * 16;

    // stage layer-1 A = sliding windows of V, hi/lo split, XOR k-group swizzle
    for (int idx = tid; idx < 64 * 160; idx += 256) {
        int m = idx / 160, k = idx - m * 160;
        int tg = t0 + m + k - (T_ENC - 1);
        float v = 0.f;
        if (k < W_IN && tg >= 0 && tg < T_DATA) v = inload(V, tg, fl);
        unsigned short hi = f2bf(v);
        int col = (((k >> 3) ^ (m & 31)) << 3) | (k & 7);
        Ahi[m * 256 + col] = hi;
        Alo[m * 256 + col] = f2bf(v - bf2f(hi));
    }
    __syncthreads();

    int arow = mbase + lm;
    int sw = (arow & 31);
    floatx4 acc[16];

    auto aoff = [&](int ks) { return arow * 256 + (((ks * 4 + quad) ^ sw) << 3); };

    auto epi = [&](const void* bias, float alpha) {
        #pragma unroll
        for (int nt = 0; nt < 16; nt++) {
            int cn = nt * 16 + lm;
            float bb = inload(bias, cn, fl);
            #pragma unroll
            for (int j = 0; j < 4; j++) {
                int row = mbase + quad * 4 + j;
                float h = acc[nt][j] + bb;
                h = (h >= 0.f) ? h : alpha * h;
                unsigned short hi = f2bf(h);
                unsigned short lo = f2bf(h - bf2f(hi));
                int col = (((cn >> 3) ^ (row & 31)) << 3) | (cn & 7);
                Ahi[row * 256 + col] = hi;
                Alo[row * 256 + col] = lo;
            }
        }
    };

    // ---- layer 1: K=160 ----
    {
        floatx4 z = {0.f, 0.f, 0.f, 0.f};
        #pragma unroll
        for (int nt = 0; nt < 16; nt++) acc[nt] = z;
        for (int ks = 0; ks < 5; ks++) {
            bf16x8 ah = *(const bf16x8*)&Ahi[aoff(ks)];
            bf16x8 al = *(const bf16x8*)&Alo[aoff(ks)];
            #pragma unroll
            for (int nt = 0; nt < 16; nt++) {
                size_t bo = (size_t)(nt * 16 + lm) * 160 + ks * 32 + quad * 8;
                bf16x8 bh = *(const bf16x8*)(W1h + bo);
                bf16x8 bl = *(const bf16x8*)(W1l + bo);
                acc[nt] = __builtin_amdgcn_mfma_f32_16x16x32_bf16(ah, bh, acc[nt], 0, 0, 0);
                acc[nt] = __builtin_amdgcn_mfma_f32_16x16x32_bf16(al, bh, acc[nt], 0, 0, 0);
                acc[nt] = __builtin_amdgcn_mfma_f32_16x16x32_bf16(ah, bl, acc[nt], 0, 0, 0);
            }
        }
        epi(b1, inload(a1p, 0, fl));
    }
    // ---- layers 2,3: K=256 ----
    const unsigned short* Whs[2] = {W2h, W3h};
    const unsigned short* Wls[2] = {W2l, W3l};
    const void* bs[2] = {b2, b3};
    const void* as_[2] = {a2p, a3p};
    for (int l = 0; l < 2; l++) {
        floatx4 z = {0.f, 0.f, 0.f, 0.f};
        #pragma unroll
        for (int nt = 0; nt < 16; nt++) acc[nt] = z;
        const unsigned short* Wh = Whs[l];
        const unsigned short* Wl = Wls[l];
        for (int ks = 0; ks < 8; ks++) {
            bf16x8 ah = *(const bf16x8*)&Ahi[aoff(ks)];
            bf16x8 al = *(const bf16x8*)&Alo[aoff(ks)];
            #pragma unroll
            for (int nt = 0; nt < 16; nt++) {
                size_t bo = (size_t)(nt * 16 + lm) * 256 + ks * 32 + quad * 8;
                bf16x8 bh = *(const bf16x8*)(Wh + bo);
                bf16x8 bl = *(const bf16x8*)(Wl + bo);
                acc[nt] = __builtin_amdgcn_mfma_f32_16x16x32_bf16(ah, bh, acc[nt], 0, 0, 0);
                acc[nt] = __builtin_amdgcn_mfma_f32_16x16x32_bf16(al, bh, acc[nt], 0, 0, 0);
                acc[nt] = __builtin_amdgcn_mfma_f32_16x16x32_bf16(ah, bl, acc[nt], 0, 0, 0);
            }
        }
        epi(bs[l], inload(as_[l], 0, fl));
    }
    // ---- layer 4: N=15 (padded to 16), K=256, + sigmoid epilogue ----
    {
        short8 z8 = {0, 0, 0, 0, 0, 0, 0, 0};
        bf16x8 bz = __builtin_bit_cast(bf16x8, z8);
        floatx4 a4 = {0.f, 0.f, 0.f, 0.f};
        for (int ks = 0; ks < 8; ks++) {
            bf16x8 ah = *(const bf16x8*)&Ahi[aoff(ks)];
            bf16x8 al = *(const bf16x8*)&Alo[aoff(ks)];
            bf16x8 bh = bz, bl = bz;
            if (lm < 15) {
                size_t bo = (size_t)lm * 256 + ks * 32 + quad * 8;
                bh = *(const bf16x8*)(W4h + bo);
                bl = *(const bf16x8*)(W4l + bo);
            }
            a4 = __builtin_amdgcn_mfma_f32_16x16x32_bf16(ah, bh, a4, 0, 0, 0);
            a4 = __builtin_amdgcn_mfma_f32_16x16x32_bf16(al, bh, a4, 0, 0, 0);
            a4 = __builtin_amdgcn_mfma_f32_16x16x32_bf16(ah, bl, a4, 0, 0, 0);
        }
        if (lm < 15) {
            float bb = inload(b4, lm, fl) + inload(encb, lm, fl);
            #pragma unroll
            for (int j = 0; j < 4; j++) {
                int row = mbase + quad * 4 + j;
                int t = t0 + row;
                if (t < T_DATA) {
                    float x = a4[j] + bb + S_conv[(size_t)t * 16 + lm + 1];
                    x = fminf(fmaxf(x, -40.f), 40.f);
                    float sg = 1.f / (1.f + expf(-x));
                    if (fl) ((unsigned short*)out)[(size_t)t * 15 + lm] = f2bf(sg);
                    else    ((float*)out)[(size_t)t * 15 + lm] = sg;
                }
            }
        }
    }
}

extern "C" void kernel_launch(void* const* d_in, const int* in_sizes, int n_in,
                              void* d_out, int out_size, void* d_ws, size_t ws_size,
                              hipStream_t stream) {
    const void* V    = d_in[0];
    const void* Se   = d_in[1];
    const void* Si   = d_in[2];
    const void* Ce   = d_in[3];
    const void* Ci   = d_in[4];
    const void* Ksyn = d_in[5];
    const void* tau  = d_in[6];
    const void* dly  = d_in[7];
    const void* encb = d_in[8];
    const void* W1   = d_in[9];
    const void* b1   = d_in[10];
    const void* a1   = d_in[11];
    const void* W2   = d_in[12];
    const void* b2   = d_in[13];
    const void* a2   = d_in[14];
    const void* W3   = d_in[15];
    const void* b3   = d_in[16];
    const void* a3   = d_in[17];
    const void* W4   = d_in[18];
    const void* b4   = d_in[19];

    char* w = (char*)d_ws;
    int* flag    = (int*)(w + OFF_FLAG);
    float* ker_e = (float*)(w + OFF_KERE);
    float* ker_i = (float*)(w + OFF_KERI);
    int* ass_e   = (int*)(w + OFF_ASSE);
    int* ass_i   = (int*)(w + OFF_ASSI);
    unsigned short* W1h = (unsigned short*)(w + OFF_W1H);
    unsigned short* W1l = (unsigned short*)(w + OFF_W1L);
    unsigned short* W2h = (unsigned short*)(w + OFF_W2H);
    unsigned short* W2l = (unsigned short*)(w + OFF_W2L);
    unsigned short* W3h = (unsigned short*)(w + OFF_W3H);
    unsigned short* W3l = (unsigned short*)(w + OFF_W3L);
    unsigned short* W4h = (unsigned short*)(w + OFF_W4H);
    unsigned short* W4l = (unsigned short*)(w + OFF_W4L);
    unsigned char* in_e = (unsigned char*)(w + OFF_INE);
    unsigned char* in_i = (unsigned char*)(w + OFF_INI);
    float* S_conv = (float*)(w + OFF_SCONV);

    k_detect<<<1, 256, 0, stream>>>((const unsigned int*)Se, flag);
    k_setup<<<722, 256, 0, stream>>>(Ksyn, tau, dly, Ce, Ci, W1, W2, W3, W4, flag,
                                     ker_e, ker_i, ass_e, ass_i,
                                     W1h, W1l, W2h, W2l, W3h, W3l, W4h, W4l);
    k_spikes<<<5000, 256, 0, stream>>>(Se, Si, ass_e, ass_i, flag, in_e, in_i);
    k_conv<<<313, 256, 0, stream>>>(in_e, in_i, ker_e, ker_i, S_conv);
    k_mlp<<<313, 256, 0, stream>>>(V, flag, W1h, W1l, b1, a1, W2h, W2l, b2, a2,
                                   W3h, W3l, b3, a3, W4h, W4l, b4,
                                   encb, S_conv, d_out);
}

// Round 3
// 459.706 us; speedup vs baseline: 1.2873x; 1.2873x over previous
//
#include <hip/hip_runtime.h>
#include <cstdint>
#include <cstddef>

#define T_DATA 20000
#define E_NO 2000
#define I_NO 500
#define SUB_NO 16
#define HID 256
#define T_SYN 200
#define T_ENC 80
#define W_IN 159   // 2*T_ENC-1

typedef __attribute__((ext_vector_type(8))) __bf16 bf16x8;
typedef __attribute__((ext_vector_type(8))) short short8;
typedef __attribute__((ext_vector_type(4))) float floatx4;
typedef __attribute__((ext_vector_type(4))) unsigned int uint4v;
typedef __attribute__((ext_vector_type(2))) unsigned int uint2v;

__device__ __forceinline__ float bf2f(unsigned short u) {
    union { unsigned int i; float f; } v; v.i = ((unsigned int)u) << 16; return v.f;
}
__device__ __forceinline__ unsigned short f2bf(float f) {
    union { float f; unsigned int i; } v; v.f = f;
    unsigned int r = v.i + 0x7FFFu + ((v.i >> 16) & 1u);
    return (unsigned short)(r >> 16);
}
__device__ __forceinline__ float inload(const void* p, int i, int isbf) {
    return isbf ? bf2f(((const unsigned short*)p)[i]) : ((const float*)p)[i];
}

// ---------------- ws layout (bytes, all 16B aligned) ----------------
#define OFF_FLAG   0u
#define OFF_KERE   16u        // 16*200 f32
#define OFF_KERI   12816u
#define OFF_ASSE   25616u     // 2000 i32
#define OFF_ASSI   33616u     // 500 i32
#define OFF_W1H    35616u     // 256*160 bf16
#define OFF_W1L    117536u
#define OFF_W2H    199456u    // 256*256 bf16
#define OFF_W2L    330528u
#define OFF_W3H    461600u
#define OFF_W3L    592672u
#define OFF_W4H    723744u    // 15*256 bf16
#define OFF_W4L    731424u
#define OFF_INE    739104u    // 20000*16 u8
#define OFF_INI    1059104u
#define OFF_SCONV  1379104u   // 20000*16 f32 ; total 2659104 bytes

// ============ kernel 0: dtype detector ============
__global__ void k_detect(const unsigned int* Se_w, int* flag) {
    __shared__ int any;
    if (threadIdx.x == 0) any = 0;
    __syncthreads();
    int la = 0;
    for (int i = threadIdx.x; i < 4096; i += 256)
        if (Se_w[i] & 0xFFFFu) la = 1;
    if (la) atomicOr(&any, 1);
    __syncthreads();
    if (threadIdx.x == 0) flag[0] = any;
}

// ================= kernel 1: setup =================
__global__ void k_setup(const void* Ksyn, const void* tau_syn, const void* dly,
                        const void* Ce, const void* Ci,
                        const void* W1, const void* W2, const void* W3, const void* W4,
                        const int* flag, float* ker_e, float* ker_i, int* ass_e, int* ass_i,
                        unsigned short* W1h, unsigned short* W1l,
                        unsigned short* W2h, unsigned short* W2l,
                        unsigned short* W3h, unsigned short* W3l,
                        unsigned short* W4h, unsigned short* W4l) {
    int f = flag[0];
    int id = blockIdx.x * 256 + threadIdx.x;
    if (id < 6400) {
        int c = id < 3200 ? 0 : 1;
        int q = id - c * 3200;
        int s = q / 200, j = q - s * 200;
        float d = expf(inload(dly, s * 2 + c, f));
        float tt = fmaxf((float)j - d, 0.0f);
        float acc = 0.f;
        #pragma unroll
        for (int b = 0; b < 3; b++) {
            float tau = expf(inload(tau_syn, b * 3 + c, f));
            float x = tt / tau;
            acc += x * expf(-x) * inload(Ksyn, (s * 3 + b) * 3 + c, f);
        }
        (c == 0 ? ker_e : ker_i)[s * 200 + j] = acc;
    } else if (id < 8400) {
        int e = id - 6400;
        int a = 0;
        for (int s = 0; s < 16; s++) if (inload(Ce, s * E_NO + e, f) > 0.5f) a = s;
        ass_e[e] = a;
    } else if (id < 8900) {
        int e = id - 8400;
        int a = 0;
        for (int s = 0; s < 16; s++) if (inload(Ci, s * I_NO + e, f) > 0.5f) a = s;
        ass_i[e] = a;
    } else if (id < 49860) {          // W1 pad 159->160 + hi/lo split
        int q = id - 8900;
        int n = q / 160, k = q - n * 160;
        float v = (k < W_IN) ? inload(W1, n * W_IN + k, f) : 0.f;
        unsigned short hi = f2bf(v);
        W1h[q] = hi;
        W1l[q] = f2bf(v - bf2f(hi));
    } else if (id < 115396) {         // W2 hi/lo
        int q = id - 49860;
        float v = inload(W2, q, f);
        unsigned short hi = f2bf(v);
        W2h[q] = hi;
        W2l[q] = f2bf(v - bf2f(hi));
    } else if (id < 180932) {         // W3 hi/lo
        int q = id - 115396;
        float v = inload(W3, q, f);
        unsigned short hi = f2bf(v);
        W3h[q] = hi;
        W3l[q] = f2bf(v - bf2f(hi));
    } else if (id < 184772) {         // W4 hi/lo
        int q = id - 180932;
        float v = inload(W4, q, f);
        unsigned short hi = f2bf(v);
        W4h[q] = hi;
        W4l[q] = f2bf(v - bf2f(hi));
    }
}

// ============ kernel 2: spike -> subunit counts (u8), wide loads ============
__global__ void k_spikes(const void* Se, const void* Si,
                         const int* ass_e, const int* ass_i, const int* flag,
                         unsigned char* in_e, unsigned char* in_i) {
    int f = flag[0];
    int lane = threadIdx.x & 63;
    int wave = threadIdx.x >> 6;
    int t = blockIdx.x * 4 + wave;
    unsigned long long e0 = 0, e1 = 0, i0 = 0, i1 = 0;
    if (f) {  // bf16: Se row = 250 x 16B, Si row = 125 x 8B
        const uint4v* re = (const uint4v*)((const unsigned short*)Se + (size_t)t * E_NO);
        #pragma unroll
        for (int it = 0; it < 4; it++) {
            int c = it * 64 + lane;
            if (c < 250) {
                uint4v v = re[c];
                #pragma unroll
                for (int w = 0; w < 4; w++) {
                    unsigned int x = v[w];
                    if (x & 0xFFFFu) {
                        int s = ass_e[c * 8 + w * 2];
                        unsigned long long inc = 1ull << ((s & 7) * 8);
                        if (s < 8) e0 += inc; else e1 += inc;
                    }
                    if (x >> 16) {
                        int s = ass_e[c * 8 + w * 2 + 1];
                        unsigned long long inc = 1ull << ((s & 7) * 8);
                        if (s < 8) e0 += inc; else e1 += inc;
                    }
                }
            }
        }
        const uint2v* ri = (const uint2v*)((const unsigned short*)Si + (size_t)t * I_NO);
        #pragma unroll
        for (int it = 0; it < 2; it++) {
            int c = it * 64 + lane;
            if (c < 125) {
                uint2v v = ri[c];
                #pragma unroll
                for (int w = 0; w < 2; w++) {
                    unsigned int x = v[w];
                    if (x & 0xFFFFu) {
                        int s = ass_i[c * 4 + w * 2];
                        unsigned long long inc = 1ull << ((s & 7) * 8);
                        if (s < 8) i0 += inc; else i1 += inc;
                    }
                    if (x >> 16) {
                        int s = ass_i[c * 4 + w * 2 + 1];
                        unsigned long long inc = 1ull << ((s & 7) * 8);
                        if (s < 8) i0 += inc; else i1 += inc;
                    }
                }
            }
        }
    } else {  // f32: Se row = 500 x 16B, Si row = 250 x 8B
        const uint4v* re = (const uint4v*)((const float*)Se + (size_t)t * E_NO);
        #pragma unroll
        for (int it = 0; it < 8; it++) {
            int c = it * 64 + lane;
            if (c < 500) {
                uint4v v = re[c];
                #pragma unroll
                for (int w = 0; w < 4; w++) {
                    if (v[w]) {
                        int s = ass_e[c * 4 + w];
                        unsigned long long inc = 1ull << ((s & 7) * 8);
                        if (s < 8) e0 += inc; else e1 += inc;
                    }
                }
            }
        }
        const uint2v* ri = (const uint2v*)((const float*)Si + (size_t)t * I_NO);
        #pragma unroll
        for (int it = 0; it < 4; it++) {
            int c = it * 64 + lane;
            if (c < 250) {
                uint2v v = ri[c];
                #pragma unroll
                for (int w = 0; w < 2; w++) {
                    if (v[w]) {
                        int s = ass_i[c * 2 + w];
                        unsigned long long inc = 1ull << ((s & 7) * 8);
                        if (s < 8) i0 += inc; else i1 += inc;
                    }
                }
            }
        }
    }
    for (int off = 32; off; off >>= 1) {
        e0 += __shfl_xor(e0, off);
        e1 += __shfl_xor(e1, off);
        i0 += __shfl_xor(i0, off);
        i1 += __shfl_xor(i1, off);
    }
    if (lane < 16) {
        unsigned long long a = (lane < 8) ? e0 : e1;
        in_e[(size_t)t * 16 + lane] = (unsigned char)((a >> ((lane & 7) * 8)) & 0xFF);
    } else if (lane < 32) {
        int s = lane - 16;
        unsigned long long a = (s < 8) ? i0 : i1;
        in_i[(size_t)t * 16 + s] = (unsigned char)((a >> ((s & 7) * 8)) & 0xFF);
    }
}

// ============ kernel 3: causal conv -> S_conv[T][16] f32 ============
__global__ void k_conv(const unsigned char* in_e, const unsigned char* in_i,
                       const float* ker_e, const float* ker_i, float* S_conv) {
    __shared__ float se[263 * 16];
    __shared__ float si[263 * 16];
    __shared__ float ke[16 * 201];
    __shared__ float ki[16 * 201];
    int t0 = blockIdx.x * 64;
    for (int idx = threadIdx.x; idx < 263 * 16; idx += 256) {
        int r = idx >> 4, s = idx & 15;
        int t = t0 - 199 + r;
        float ve = 0.f, vi = 0.f;
        if (t >= 0 && t < T_DATA) {
            ve = (float)in_e[(size_t)t * 16 + s];
            vi = (float)in_i[(size_t)t * 16 + s];
        }
        se[idx] = ve; si[idx] = vi;
    }
    for (int idx = threadIdx.x; idx < 3200; idx += 256) {
        int s = idx / 200, j = idx - s * 200;
        ke[s * 201 + j] = ker_e[idx];
        ki[s * 201 + j] = ker_i[idx];
    }
    __syncthreads();
    #pragma unroll
    for (int p = 0; p < 4; p++) {
        int idx = p * 256 + threadIdx.x;
        int tl = idx >> 4, s = idx & 15;
        int t = t0 + tl;
        if (t < T_DATA) {
            float acc = 0.f;
            #pragma unroll 4
            for (int j = 0; j < 200; j++) {
                int r = (tl + 199 - j) * 16 + s;
                acc += se[r] * ke[s * 201 + j];
                acc += si[r] * ki[s * 201 + j];
            }
            S_conv[(size_t)t * 16 + s] = acc;
        }
    }
}

// ============ kernel 4: fused sliding-window MLP ============
// 16 timesteps/block, 4 waves; wave c computes output cols [64c, 64c+64) each
// layer; __syncthreads around each epilogue. LDS = 16 KB -> ~5 blocks/CU, grid
// 1250 -> ~20 waves/CU resident in ONE generation (was 4.9 at 64 KB / 313 blocks).
// A carried hi+lo bf16 (captures f32->bf16 rounding of h); W-lo MFMAs only in
// the f32-input case (in bf16 mode W-lo == 0 exactly, so skipping is identical).
template<bool BF>
__device__ __forceinline__ void mlp_body(
    const void* V,
    const unsigned short* W1h, const unsigned short* W1l, const void* b1, const void* a1p,
    const unsigned short* W2h, const unsigned short* W2l, const void* b2, const void* a2p,
    const unsigned short* W3h, const unsigned short* W3l, const void* b3, const void* a3p,
    const unsigned short* W4h, const unsigned short* W4l, const void* b4,
    const void* encb, const float* S_conv, void* out,
    unsigned short* Ahi, unsigned short* Alo)
{
    int tid = threadIdx.x;
    int lane = tid & 63, wave = tid >> 6;
    int lm = lane & 15, quad = lane >> 4;
    int t0 = blockIdx.x * 16;

    auto ld = [&](const void* p, int i) -> float {
        return BF ? bf2f(((const unsigned short*)p)[i]) : ((const float*)p)[i];
    };

    // stage layer-1 A: 16 rows x 160 window cols, hi/lo, XOR group swizzle
    for (int idx = tid; idx < 16 * 160; idx += 256) {
        int m = idx / 160, k = idx - m * 160;
        int tg = t0 + m + k - (T_ENC - 1);
        float v = 0.f;
        if (k < W_IN && tg >= 0 && tg < T_DATA) v = ld(V, tg);
        unsigned short hi = f2bf(v);
        int col = (((k >> 3) ^ m) << 3) | (k & 7);
        Ahi[m * 256 + col] = hi;
        Alo[m * 256 + col] = f2bf(v - bf2f(hi));
    }
    __syncthreads();

    floatx4 acc[4];
    auto aoff = [&](int ks) { return lm * 256 + (((((ks << 2) | quad)) ^ lm) << 3); };

    auto epi = [&](const void* bias, float alpha) {
        __syncthreads();   // all waves done READING this layer's A
        #pragma unroll
        for (int nt = 0; nt < 4; nt++) {
            int cn = wave * 64 + nt * 16 + lm;
            float bb = ld(bias, cn);
            #pragma unroll
            for (int j = 0; j < 4; j++) {
                int row = quad * 4 + j;
                float h = acc[nt][j] + bb;
                h = (h >= 0.f) ? h : alpha * h;
                unsigned short hi = f2bf(h);
                int col = (((cn >> 3) ^ row) << 3) | (cn & 7);
                Ahi[row * 256 + col] = hi;
                Alo[row * 256 + col] = f2bf(h - bf2f(hi));
            }
        }
        __syncthreads();   // writes visible to all waves
    };

    // ---- layer 1: K=160 (5 ks groups) ----
    {
        floatx4 z = {0.f, 0.f, 0.f, 0.f};
        #pragma unroll
        for (int nt = 0; nt < 4; nt++) acc[nt] = z;
        #pragma unroll
        for (int ks = 0; ks < 5; ks++) {
            bf16x8 ah = *(const bf16x8*)&Ahi[aoff(ks)];
            bf16x8 al = *(const bf16x8*)&Alo[aoff(ks)];
            #pragma unroll
            for (int nt = 0; nt < 4; nt++) {
                int cn = wave * 64 + nt * 16 + lm;
                size_t bo = (size_t)cn * 160 + ks * 32 + quad * 8;
                bf16x8 bh = *(const bf16x8*)(W1h + bo);
                acc[nt] = __builtin_amdgcn_mfma_f32_16x16x32_bf16(ah, bh, acc[nt], 0, 0, 0);
                acc[nt] = __builtin_amdgcn_mfma_f32_16x16x32_bf16(al, bh, acc[nt], 0, 0, 0);
                if (!BF) {
                    bf16x8 bl = *(const bf16x8*)(W1l + bo);
                    acc[nt] = __builtin_amdgcn_mfma_f32_16x16x32_bf16(ah, bl, acc[nt], 0, 0, 0);
                }
            }
        }
        epi(b1, ld(a1p, 0));
    }
    // ---- layers 2,3: K=256 (8 ks groups) ----
    const unsigned short* Whs[2] = {W2h, W3h};
    const unsigned short* Wls[2] = {W2l, W3l};
    const void* bs[2] = {b2, b3};
    const void* as_[2] = {a2p, a3p};
    for (int l = 0; l < 2; l++) {
        floatx4 z = {0.f, 0.f, 0.f, 0.f};
        #pragma unroll
        for (int nt = 0; nt < 4; nt++) acc[nt] = z;
        const unsigned short* Wh = Whs[l];
        const unsigned short* Wl = Wls[l];
        #pragma unroll
        for (int ks = 0; ks < 8; ks++) {
            bf16x8 ah = *(const bf16x8*)&Ahi[aoff(ks)];
            bf16x8 al = *(const bf16x8*)&Alo[aoff(ks)];
            #pragma unroll
            for (int nt = 0; nt < 4; nt++) {
                int cn = wave * 64 + nt * 16 + lm;
                size_t bo = (size_t)cn * 256 + ks * 32 + quad * 8;
                bf16x8 bh = *(const bf16x8*)(Wh + bo);
                acc[nt] = __builtin_amdgcn_mfma_f32_16x16x32_bf16(ah, bh, acc[nt], 0, 0, 0);
                acc[nt] = __builtin_amdgcn_mfma_f32_16x16x32_bf16(al, bh, acc[nt], 0, 0, 0);
                if (!BF) {
                    bf16x8 bl = *(const bf16x8*)(Wl + bo);
                    acc[nt] = __builtin_amdgcn_mfma_f32_16x16x32_bf16(ah, bl, acc[nt], 0, 0, 0);
                }
            }
        }
        epi(bs[l], ld(as_[l], 0));
    }
    // ---- layer 4: N=15 (one 16-col tile; wave 0 only) + sigmoid ----
    if (wave == 0) {
        short8 z8 = {0, 0, 0, 0, 0, 0, 0, 0};
        bf16x8 bz = __builtin_bit_cast(bf16x8, z8);
        floatx4 a4 = {0.f, 0.f, 0.f, 0.f};
        #pragma unroll
        for (int ks = 0; ks < 8; ks++) {
            bf16x8 ah = *(const bf16x8*)&Ahi[aoff(ks)];
            bf16x8 al = *(const bf16x8*)&Alo[aoff(ks)];
            bf16x8 bh = bz, bl = bz;
            if (lm < 15) {
                size_t bo = (size_t)lm * 256 + ks * 32 + quad * 8;
                bh = *(const bf16x8*)(W4h + bo);
                if (!BF) bl = *(const bf16x8*)(W4l + bo);
            }
            a4 = __builtin_amdgcn_mfma_f32_16x16x32_bf16(ah, bh, a4, 0, 0, 0);
            a4 = __builtin_amdgcn_mfma_f32_16x16x32_bf16(al, bh, a4, 0, 0, 0);
            if (!BF)
                a4 = __builtin_amdgcn_mfma_f32_16x16x32_bf16(ah, bl, a4, 0, 0, 0);
        }
        if (lm < 15) {
            float bb = ld(b4, lm) + ld(encb, lm);
            #pragma unroll
            for (int j = 0; j < 4; j++) {
                int row = quad * 4 + j;
                int t = t0 + row;
                float x = a4[j] + bb + S_conv[(size_t)t * 16 + lm + 1];
                x = fminf(fmaxf(x, -40.f), 40.f);
                float sg = 1.f / (1.f + expf(-x));
                if (BF) ((unsigned short*)out)[(size_t)t * 15 + lm] = f2bf(sg);
                else    ((float*)out)[(size_t)t * 15 + lm] = sg;
            }
        }
    }
}

__global__ void __launch_bounds__(256) k_mlp(
    const void* V, const int* flag,
    const unsigned short* W1h, const unsigned short* W1l, const void* b1, const void* a1p,
    const unsigned short* W2h, const unsigned short* W2l, const void* b2, const void* a2p,
    const unsigned short* W3h, const unsigned short* W3l, const void* b3, const void* a3p,
    const unsigned short* W4h, const unsigned short* W4l, const void* b4,
    const void* encb, const float* S_conv, void* out) {
    __shared__ __align__(16) unsigned short Ahi[16 * 256];
    __shared__ __align__(16) unsigned short Alo[16 * 256];
    if (flag[0])
        mlp_body<true>(V, W1h, W1l, b1, a1p, W2h, W2l, b2, a2p, W3h, W3l, b3, a3p,
                       W4h, W4l, b4, encb, S_conv, out, Ahi, Alo);
    else
        mlp_body<false>(V, W1h, W1l, b1, a1p, W2h, W2l, b2, a2p, W3h, W3l, b3, a3p,
                        W4h, W4l, b4, encb, S_conv, out, Ahi, Alo);
}

extern "C" void kernel_launch(void* const* d_in, const int* in_sizes, int n_in,
                              void* d_out, int out_size, void* d_ws, size_t ws_size,
                              hipStream_t stream) {
    const void* V    = d_in[0];
    const void* Se   = d_in[1];
    const void* Si   = d_in[2];
    const void* Ce   = d_in[3];
    const void* Ci   = d_in[4];
    const void* Ksyn = d_in[5];
    const void* tau  = d_in[6];
    const void* dly  = d_in[7];
    const void* encb = d_in[8];
    const void* W1   = d_in[9];
    const void* b1   = d_in[10];
    const void* a1   = d_in[11];
    const void* W2   = d_in[12];
    const void* b2   = d_in[13];
    const void* a2   = d_in[14];
    const void* W3   = d_in[15];
    const void* b3   = d_in[16];
    const void* a3   = d_in[17];
    const void* W4   = d_in[18];
    const void* b4   = d_in[19];

    char* w = (char*)d_ws;
    int* flag    = (int*)(w + OFF_FLAG);
    float* ker_e = (float*)(w + OFF_KERE);
    float* ker_i = (float*)(w + OFF_KERI);
    int* ass_e   = (int*)(w + OFF_ASSE);
    int* ass_i   = (int*)(w + OFF_ASSI);
    unsigned short* W1h = (unsigned short*)(w + OFF_W1H);
    unsigned short* W1l = (unsigned short*)(w + OFF_W1L);
    unsigned short* W2h = (unsigned short*)(w + OFF_W2H);
    unsigned short* W2l = (unsigned short*)(w + OFF_W2L);
    unsigned short* W3h = (unsigned short*)(w + OFF_W3H);
    unsigned short* W3l = (unsigned short*)(w + OFF_W3L);
    unsigned short* W4h = (unsigned short*)(w + OFF_W4H);
    unsigned short* W4l = (unsigned short*)(w + OFF_W4L);
    unsigned char* in_e = (unsigned char*)(w + OFF_INE);
    unsigned char* in_i = (unsigned char*)(w + OFF_INI);
    float* S_conv = (float*)(w + OFF_SCONV);

    k_detect<<<1, 256, 0, stream>>>((const unsigned int*)Se, flag);
    k_setup<<<722, 256, 0, stream>>>(Ksyn, tau, dly, Ce, Ci, W1, W2, W3, W4, flag,
                                     ker_e, ker_i, ass_e, ass_i,
                                     W1h, W1l, W2h, W2l, W3h, W3l, W4h, W4l);
    k_spikes<<<5000, 256, 0, stream>>>(Se, Si, ass_e, ass_i, flag, in_e, in_i);
    k_conv<<<313, 256, 0, stream>>>(in_e, in_i, ker_e, ker_i, S_conv);
    k_mlp<<<1250, 256, 0, stream>>>(V, flag, W1h, W1l, b1, a1, W2h, W2l, b2, a2,
                                    W3h, W3l, b3, a3, W4h, W4l, b4,
                                    encb, S_conv, d_out);
}

// Round 4
// 415.565 us; speedup vs baseline: 1.4240x; 1.1062x over previous
//
#include <hip/hip_runtime.h>
#include <cstdint>
#include <cstddef>

#define T_DATA 20000
#define E_NO 2000
#define I_NO 500
#define SUB_NO 16
#define HID 256
#define T_SYN 200
#define T_ENC 80
#define W_IN 159   // 2*T_ENC-1

typedef __attribute__((ext_vector_type(8))) __bf16 bf16x8;
typedef __attribute__((ext_vector_type(8))) short short8;
typedef __attribute__((ext_vector_type(4))) float floatx4;
typedef __attribute__((ext_vector_type(4))) unsigned int uint4v;
typedef __attribute__((ext_vector_type(2))) unsigned int uint2v;

__device__ __forceinline__ float bf2f(unsigned short u) {
    union { unsigned int i; float f; } v; v.i = ((unsigned int)u) << 16; return v.f;
}
__device__ __forceinline__ unsigned short f2bf(float f) {
    union { float f; unsigned int i; } v; v.f = f;
    unsigned int r = v.i + 0x7FFFu + ((v.i >> 16) & 1u);
    return (unsigned short)(r >> 16);
}
__device__ __forceinline__ float inload(const void* p, int i, int isbf) {
    return isbf ? bf2f(((const unsigned short*)p)[i]) : ((const float*)p)[i];
}

// per-block dtype detection: scan first 1024 u32 words of S_e (4 KB, L2-hot).
// f32 spikes (0x0 / 0x3F800000) have low16==0 always; bf16 pairs hit low16
// ~2%/word -> P(false f32 verdict) ~ e^-20. Requires blockDim.x == 256.
__device__ __forceinline__ int detect_bf(const void* Se, int* sfl) {
    if (threadIdx.x == 0) *sfl = 0;
    __syncthreads();
    const unsigned int* w = (const unsigned int*)Se;
    int la = 0;
    #pragma unroll
    for (int i = 0; i < 4; i++)
        la |= (w[i * 256 + threadIdx.x] & 0xFFFFu) ? 1 : 0;
    if (la) atomicOr(sfl, 1);
    __syncthreads();
    return *sfl;
}

// ---------------- ws layout (bytes, all 16B aligned) ----------------
#define OFF_KERE   16u        // 16*200 f32
#define OFF_KERI   12816u
#define OFF_ASSE   25616u     // 2000 i32
#define OFF_ASSI   33616u     // 500 i32
#define OFF_W1H    35616u     // 256*160 bf16
#define OFF_W1L    117536u
#define OFF_W2H    199456u    // 256*256 bf16
#define OFF_W2L    330528u
#define OFF_W3H    461600u
#define OFF_W3L    592672u
#define OFF_W4H    723744u    // 15*256 bf16
#define OFF_W4L    731424u
#define OFF_INE    739104u    // 20000*16 u8
#define OFF_INI    1059104u
#define OFF_SCONV  1379104u   // 20000*16 f32 ; total 2659104 bytes

// ================= kernel 1: setup =================
__global__ void k_setup(const void* Se, const void* Ksyn, const void* tau_syn, const void* dly,
                        const void* Ce, const void* Ci,
                        const void* W1, const void* W2, const void* W3, const void* W4,
                        float* ker_e, float* ker_i, int* ass_e, int* ass_i,
                        unsigned short* W1h, unsigned short* W1l,
                        unsigned short* W2h, unsigned short* W2l,
                        unsigned short* W3h, unsigned short* W3l,
                        unsigned short* W4h, unsigned short* W4l) {
    __shared__ int sfl;
    int f = detect_bf(Se, &sfl);
    int id = blockIdx.x * 256 + threadIdx.x;
    if (id < 6400) {
        int c = id < 3200 ? 0 : 1;
        int q = id - c * 3200;
        int s = q / 200, j = q - s * 200;
        float d = expf(inload(dly, s * 2 + c, f));
        float tt = fmaxf((float)j - d, 0.0f);
        float acc = 0.f;
        #pragma unroll
        for (int b = 0; b < 3; b++) {
            float tau = expf(inload(tau_syn, b * 3 + c, f));
            float x = tt / tau;
            acc += x * expf(-x) * inload(Ksyn, (s * 3 + b) * 3 + c, f);
        }
        (c == 0 ? ker_e : ker_i)[s * 200 + j] = acc;
    } else if (id < 8400) {
        int e = id - 6400;
        int a = 0;
        for (int s = 0; s < 16; s++) if (inload(Ce, s * E_NO + e, f) > 0.5f) a = s;
        ass_e[e] = a;
    } else if (id < 8900) {
        int e = id - 8400;
        int a = 0;
        for (int s = 0; s < 16; s++) if (inload(Ci, s * I_NO + e, f) > 0.5f) a = s;
        ass_i[e] = a;
    } else if (id < 49860) {          // W1 pad 159->160 + hi/lo split
        int q = id - 8900;
        int n = q / 160, k = q - n * 160;
        float v = (k < W_IN) ? inload(W1, n * W_IN + k, f) : 0.f;
        unsigned short hi = f2bf(v);
        W1h[q] = hi;
        W1l[q] = f2bf(v - bf2f(hi));
    } else if (id < 115396) {         // W2 hi/lo
        int q = id - 49860;
        float v = inload(W2, q, f);
        unsigned short hi = f2bf(v);
        W2h[q] = hi;
        W2l[q] = f2bf(v - bf2f(hi));
    } else if (id < 180932) {         // W3 hi/lo
        int q = id - 115396;
        float v = inload(W3, q, f);
        unsigned short hi = f2bf(v);
        W3h[q] = hi;
        W3l[q] = f2bf(v - bf2f(hi));
    } else if (id < 184772) {         // W4 hi/lo
        int q = id - 180932;
        float v = inload(W4, q, f);
        unsigned short hi = f2bf(v);
        W4h[q] = hi;
        W4l[q] = f2bf(v - bf2f(hi));
    }
}

// ============ kernel 2: spike -> subunit counts (u8), wide loads ============
__global__ void k_spikes(const void* Se, const void* Si,
                         const int* ass_e, const int* ass_i,
                         unsigned char* in_e, unsigned char* in_i) {
    __shared__ int sfl;
    int f = detect_bf(Se, &sfl);
    int lane = threadIdx.x & 63;
    int wave = threadIdx.x >> 6;
    int t = blockIdx.x * 4 + wave;
    unsigned long long e0 = 0, e1 = 0, i0 = 0, i1 = 0;
    if (f) {  // bf16: Se row = 250 x 16B, Si row = 125 x 8B
        const uint4v* re = (const uint4v*)((const unsigned short*)Se + (size_t)t * E_NO);
        #pragma unroll
        for (int it = 0; it < 4; it++) {
            int c = it * 64 + lane;
            if (c < 250) {
                uint4v v = re[c];
                #pragma unroll
                for (int w = 0; w < 4; w++) {
                    unsigned int x = v[w];
                    if (x & 0xFFFFu) {
                        int s = ass_e[c * 8 + w * 2];
                        unsigned long long inc = 1ull << ((s & 7) * 8);
                        if (s < 8) e0 += inc; else e1 += inc;
                    }
                    if (x >> 16) {
                        int s = ass_e[c * 8 + w * 2 + 1];
                        unsigned long long inc = 1ull << ((s & 7) * 8);
                        if (s < 8) e0 += inc; else e1 += inc;
                    }
                }
            }
        }
        const uint2v* ri = (const uint2v*)((const unsigned short*)Si + (size_t)t * I_NO);
        #pragma unroll
        for (int it = 0; it < 2; it++) {
            int c = it * 64 + lane;
            if (c < 125) {
                uint2v v = ri[c];
                #pragma unroll
                for (int w = 0; w < 2; w++) {
                    unsigned int x = v[w];
                    if (x & 0xFFFFu) {
                        int s = ass_i[c * 4 + w * 2];
                        unsigned long long inc = 1ull << ((s & 7) * 8);
                        if (s < 8) i0 += inc; else i1 += inc;
                    }
                    if (x >> 16) {
                        int s = ass_i[c * 4 + w * 2 + 1];
                        unsigned long long inc = 1ull << ((s & 7) * 8);
                        if (s < 8) i0 += inc; else i1 += inc;
                    }
                }
            }
        }
    } else {  // f32
        const uint4v* re = (const uint4v*)((const float*)Se + (size_t)t * E_NO);
        #pragma unroll
        for (int it = 0; it < 8; it++) {
            int c = it * 64 + lane;
            if (c < 500) {
                uint4v v = re[c];
                #pragma unroll
                for (int w = 0; w < 4; w++) {
                    if (v[w]) {
                        int s = ass_e[c * 4 + w];
                        unsigned long long inc = 1ull << ((s & 7) * 8);
                        if (s < 8) e0 += inc; else e1 += inc;
                    }
                }
            }
        }
        const uint2v* ri = (const uint2v*)((const float*)Si + (size_t)t * I_NO);
        #pragma unroll
        for (int it = 0; it < 4; it++) {
            int c = it * 64 + lane;
            if (c < 250) {
                uint2v v = ri[c];
                #pragma unroll
                for (int w = 0; w < 2; w++) {
                    if (v[w]) {
                        int s = ass_i[c * 2 + w];
                        unsigned long long inc = 1ull << ((s & 7) * 8);
                        if (s < 8) i0 += inc; else i1 += inc;
                    }
                }
            }
        }
    }
    for (int off = 32; off; off >>= 1) {
        e0 += __shfl_xor(e0, off);
        e1 += __shfl_xor(e1, off);
        i0 += __shfl_xor(i0, off);
        i1 += __shfl_xor(i1, off);
    }
    if (lane < 16) {
        unsigned long long a = (lane < 8) ? e0 : e1;
        in_e[(size_t)t * 16 + lane] = (unsigned char)((a >> ((lane & 7) * 8)) & 0xFF);
    } else if (lane < 32) {
        int s = lane - 16;
        unsigned long long a = (s < 8) ? i0 : i1;
        in_i[(size_t)t * 16 + s] = (unsigned char)((a >> ((s & 7) * 8)) & 0xFF);
    }
}

// ============ kernel 3: causal conv, register sliding-window ============
// thread = (s, 4 consecutive t); per j: 4 LDS reads feed 8 FMAs (4x fewer
// reads than the naive form). Row pad 17 breaks the 4-way se bank conflict.
__global__ void __launch_bounds__(256) k_conv(
        const unsigned char* in_e, const unsigned char* in_i,
        const float* ker_e, const float* ker_i, float* S_conv) {
    __shared__ float se[263 * 17];
    __shared__ float si[263 * 17];
    __shared__ float ke[16 * 201];
    __shared__ float ki[16 * 201];
    int t0 = blockIdx.x * 64;
    // stage counts (u32 = 4 subunits), zero-pad out of range
    for (int idx = threadIdx.x; idx < 263 * 4; idx += 256) {
        int r = idx >> 2, wi = idx & 3;
        int t = t0 - 199 + r;
        unsigned int ve = 0, vi = 0;
        if (t >= 0 && t < T_DATA) {
            ve = ((const unsigned int*)in_e)[t * 4 + wi];
            vi = ((const unsigned int*)in_i)[t * 4 + wi];
        }
        #pragma unroll
        for (int b = 0; b < 4; b++) {
            se[r * 17 + wi * 4 + b] = (float)((ve >> (8 * b)) & 0xFF);
            si[r * 17 + wi * 4 + b] = (float)((vi >> (8 * b)) & 0xFF);
        }
    }
    for (int idx = threadIdx.x; idx < 3200; idx += 256) {
        int s = idx / 200, j = idx - s * 200;
        ke[s * 201 + j] = ker_e[idx];
        ki[s * 201 + j] = ker_i[idx];
    }
    __syncthreads();
    int s = threadIdx.x & 15, g4 = (threadIdx.x >> 4) * 4;
    float a0 = 0.f, a1 = 0.f, a2 = 0.f, a3 = 0.f;
    // window regs: w[q] <-> row g4+q+199-j
    float w0 = se[(g4 + 199) * 17 + s], w1 = se[(g4 + 200) * 17 + s];
    float w2 = se[(g4 + 201) * 17 + s], w3 = se[(g4 + 202) * 17 + s];
    float x0 = si[(g4 + 199) * 17 + s], x1 = si[(g4 + 200) * 17 + s];
    float x2 = si[(g4 + 201) * 17 + s], x3 = si[(g4 + 202) * 17 + s];
    #pragma unroll 4
    for (int j = 0; j < 200; j++) {
        float kej = ke[s * 201 + j];
        float kij = ki[s * 201 + j];
        a0 += w0 * kej + x0 * kij;
        a1 += w1 * kej + x1 * kij;
        a2 += w2 * kej + x2 * kij;
        a3 += w3 * kej + x3 * kij;
        int lr = g4 + 198 - j; lr = lr < 0 ? 0 : lr;   // last-iter load unused
        float nw = se[lr * 17 + s], nx = si[lr * 17 + s];
        w3 = w2; w2 = w1; w1 = w0; w0 = nw;
        x3 = x2; x2 = x1; x1 = x0; x0 = nx;
    }
    int tb = t0 + g4;
    if (tb + 0 < T_DATA) S_conv[(size_t)(tb + 0) * 16 + s] = a0;
    if (tb + 1 < T_DATA) S_conv[(size_t)(tb + 1) * 16 + s] = a1;
    if (tb + 2 < T_DATA) S_conv[(size_t)(tb + 2) * 16 + s] = a2;
    if (tb + 3 < T_DATA) S_conv[(size_t)(tb + 3) * 16 + s] = a3;
}

// ============ kernel 4: fused sliding-window MLP ============
// 32 timesteps/block (2 M-tiles), 4 waves; wave w owns cols [64w,64w+64).
// Every B-load now feeds 2 M-tiles (2x L2 traffic cut) and 8 independent
// MFMA chains/wave (2x ILP). LDS 32 KB -> 5 blocks/CU possible.
template<bool BF>
__device__ __forceinline__ void mlp_body(
    const void* V,
    const unsigned short* W1h, const unsigned short* W1l, const void* b1, const void* a1p,
    const unsigned short* W2h, const unsigned short* W2l, const void* b2, const void* a2p,
    const unsigned short* W3h, const unsigned short* W3l, const void* b3, const void* a3p,
    const unsigned short* W4h, const unsigned short* W4l, const void* b4,
    const void* encb, const float* S_conv, void* out,
    unsigned short* Ahi, unsigned short* Alo)
{
    int tid = threadIdx.x;
    int lane = tid & 63, wave = tid >> 6;
    int lm = lane & 15, quad = lane >> 4;
    int t0 = blockIdx.x * 32;

    auto ld = [&](const void* p, int i) -> float {
        return BF ? bf2f(((const unsigned short*)p)[i]) : ((const float*)p)[i];
    };

    // stage layer-1 A: 32 rows x 160 cols, hi/lo, XOR chunk swizzle
    for (int idx = tid; idx < 32 * 160; idx += 256) {
        int m = idx / 160, k = idx - m * 160;
        int tg = t0 + m + k - (T_ENC - 1);
        float v = 0.f;
        if (k < W_IN && tg >= 0 && tg < T_DATA) v = ld(V, tg);
        unsigned short hi = f2bf(v);
        int col = (((k >> 3) ^ m) << 3) | (k & 7);
        Ahi[m * 256 + col] = hi;
        Alo[m * 256 + col] = f2bf(v - bf2f(hi));
    }
    __syncthreads();

    floatx4 acc[2][4];
    auto aoff = [&](int mt, int ks) {
        int arow = mt * 16 + lm;
        return arow * 256 + ((((ks << 2) | quad) ^ arow) << 3);
    };

    auto epi = [&](const void* bias, float alpha) {
        __syncthreads();   // all waves done READING this layer's A
        #pragma unroll
        for (int mt = 0; mt < 2; mt++) {
            #pragma unroll
            for (int nt = 0; nt < 4; nt++) {
                int cn = wave * 64 + nt * 16 + lm;
                float bb = ld(bias, cn);
                #pragma unroll
                for (int j = 0; j < 4; j++) {
                    int row = mt * 16 + quad * 4 + j;
                    float h = acc[mt][nt][j] + bb;
                    h = (h >= 0.f) ? h : alpha * h;
                    unsigned short hi = f2bf(h);
                    int col = (((cn >> 3) ^ row) << 3) | (cn & 7);
                    Ahi[row * 256 + col] = hi;
                    Alo[row * 256 + col] = f2bf(h - bf2f(hi));
                }
            }
        }
        __syncthreads();   // writes visible to all waves
    };

    floatx4 z = {0.f, 0.f, 0.f, 0.f};
    // ---- layer 1: K=160 (5 ks). In BF mode V is exact bf16 -> A-lo==0 and
    // W1-lo==0, so only the hi*hi MFMA is nonzero.
    {
        #pragma unroll
        for (int mt = 0; mt < 2; mt++)
            #pragma unroll
            for (int nt = 0; nt < 4; nt++) acc[mt][nt] = z;
        #pragma unroll
        for (int ks = 0; ks < 5; ks++) {
            bf16x8 ah0 = *(const bf16x8*)&Ahi[aoff(0, ks)];
            bf16x8 ah1 = *(const bf16x8*)&Ahi[aoff(1, ks)];
            bf16x8 al0, al1;
            if (!BF) { al0 = *(const bf16x8*)&Alo[aoff(0, ks)];
                       al1 = *(const bf16x8*)&Alo[aoff(1, ks)]; }
            #pragma unroll
            for (int nt = 0; nt < 4; nt++) {
                int cn = wave * 64 + nt * 16 + lm;
                size_t bo = (size_t)cn * 160 + ks * 32 + quad * 8;
                bf16x8 bh = *(const bf16x8*)(W1h + bo);
                acc[0][nt] = __builtin_amdgcn_mfma_f32_16x16x32_bf16(ah0, bh, acc[0][nt], 0, 0, 0);
                acc[1][nt] = __builtin_amdgcn_mfma_f32_16x16x32_bf16(ah1, bh, acc[1][nt], 0, 0, 0);
                if (!BF) {
                    bf16x8 bl = *(const bf16x8*)(W1l + bo);
                    acc[0][nt] = __builtin_amdgcn_mfma_f32_16x16x32_bf16(al0, bh, acc[0][nt], 0, 0, 0);
                    acc[1][nt] = __builtin_amdgcn_mfma_f32_16x16x32_bf16(al1, bh, acc[1][nt], 0, 0, 0);
                    acc[0][nt] = __builtin_amdgcn_mfma_f32_16x16x32_bf16(ah0, bl, acc[0][nt], 0, 0, 0);
                    acc[1][nt] = __builtin_amdgcn_mfma_f32_16x16x32_bf16(ah1, bl, acc[1][nt], 0, 0, 0);
                }
            }
        }
        epi(b1, ld(a1p, 0));
    }
    // ---- layers 2,3: K=256 (8 ks); A-lo always needed (h rounding) ----
    const unsigned short* Whs[2] = {W2h, W3h};
    const unsigned short* Wls[2] = {W2l, W3l};
    const void* bs[2] = {b2, b3};
    const void* as_[2] = {a2p, a3p};
    for (int l = 0; l < 2; l++) {
        #pragma unroll
        for (int mt = 0; mt < 2; mt++)
            #pragma unroll
            for (int nt = 0; nt < 4; nt++) acc[mt][nt] = z;
        const unsigned short* Wh = Whs[l];
        const unsigned short* Wl = Wls[l];
        #pragma unroll
        for (int ks = 0; ks < 8; ks++) {
            bf16x8 ah0 = *(const bf16x8*)&Ahi[aoff(0, ks)];
            bf16x8 ah1 = *(const bf16x8*)&Ahi[aoff(1, ks)];
            bf16x8 al0 = *(const bf16x8*)&Alo[aoff(0, ks)];
            bf16x8 al1 = *(const bf16x8*)&Alo[aoff(1, ks)];
            #pragma unroll
            for (int nt = 0; nt < 4; nt++) {
                int cn = wave * 64 + nt * 16 + lm;
                size_t bo = (size_t)cn * 256 + ks * 32 + quad * 8;
                bf16x8 bh = *(const bf16x8*)(Wh + bo);
                acc[0][nt] = __builtin_amdgcn_mfma_f32_16x16x32_bf16(ah0, bh, acc[0][nt], 0, 0, 0);
                acc[1][nt] = __builtin_amdgcn_mfma_f32_16x16x32_bf16(ah1, bh, acc[1][nt], 0, 0, 0);
                acc[0][nt] = __builtin_amdgcn_mfma_f32_16x16x32_bf16(al0, bh, acc[0][nt], 0, 0, 0);
                acc[1][nt] = __builtin_amdgcn_mfma_f32_16x16x32_bf16(al1, bh, acc[1][nt], 0, 0, 0);
                if (!BF) {
                    bf16x8 bl = *(const bf16x8*)(Wl + bo);
                    acc[0][nt] = __builtin_amdgcn_mfma_f32_16x16x32_bf16(ah0, bl, acc[0][nt], 0, 0, 0);
                    acc[1][nt] = __builtin_amdgcn_mfma_f32_16x16x32_bf16(ah1, bl, acc[1][nt], 0, 0, 0);
                }
            }
        }
        epi(bs[l], ld(as_[l], 0));
    }
    // ---- layer 4: N=15 (16-padded), waves 0/1 take one M-tile each ----
    if (wave < 2) {
        int mt = wave;
        short8 z8 = {0, 0, 0, 0, 0, 0, 0, 0};
        bf16x8 bz = __builtin_bit_cast(bf16x8, z8);
        floatx4 a4 = z;
        #pragma unroll
        for (int ks = 0; ks < 8; ks++) {
            bf16x8 ah = *(const bf16x8*)&Ahi[aoff(mt, ks)];
            bf16x8 al = *(const bf16x8*)&Alo[aoff(mt, ks)];
            bf16x8 bh = bz, bl = bz;
            if (lm < 15) {
                size_t bo = (size_t)lm * 256 + ks * 32 + quad * 8;
                bh = *(const bf16x8*)(W4h + bo);
                if (!BF) bl = *(const bf16x8*)(W4l + bo);
            }
            a4 = __builtin_amdgcn_mfma_f32_16x16x32_bf16(ah, bh, a4, 0, 0, 0);
            a4 = __builtin_amdgcn_mfma_f32_16x16x32_bf16(al, bh, a4, 0, 0, 0);
            if (!BF)
                a4 = __builtin_amdgcn_mfma_f32_16x16x32_bf16(ah, bl, a4, 0, 0, 0);
        }
        if (lm < 15) {
            float bb = ld(b4, lm) + ld(encb, lm);
            #pragma unroll
            for (int j = 0; j < 4; j++) {
                int row = mt * 16 + quad * 4 + j;
                int t = t0 + row;
                float x = a4[j] + bb + S_conv[(size_t)t * 16 + lm + 1];
                x = fminf(fmaxf(x, -40.f), 40.f);
                float sg = 1.f / (1.f + expf(-x));
                if (BF) ((unsigned short*)out)[(size_t)t * 15 + lm] = f2bf(sg);
                else    ((float*)out)[(size_t)t * 15 + lm] = sg;
            }
        }
    }
}

__global__ void __launch_bounds__(256) k_mlp(
    const void* Se, const void* V,
    const unsigned short* W1h, const unsigned short* W1l, const void* b1, const void* a1p,
    const unsigned short* W2h, const unsigned short* W2l, const void* b2, const void* a2p,
    const unsigned short* W3h, const unsigned short* W3l, const void* b3, const void* a3p,
    const unsigned short* W4h, const unsigned short* W4l, const void* b4,
    const void* encb, const float* S_conv, void* out) {
    __shared__ __align__(16) unsigned short Ahi[32 * 256];
    __shared__ __align__(16) unsigned short Alo[32 * 256];
    __shared__ int sfl;
    int f = detect_bf(Se, &sfl);
    if (f)
        mlp_body<true>(V, W1h, W1l, b1, a1p, W2h, W2l, b2, a2p, W3h, W3l, b3, a3p,
                       W4h, W4l, b4, encb, S_conv, out, Ahi, Alo);
    else
        mlp_body<false>(V, W1h, W1l, b1, a1p, W2h, W2l, b2, a2p, W3h, W3l, b3, a3p,
                        W4h, W4l, b4, encb, S_conv, out, Ahi, Alo);
}

extern "C" void kernel_launch(void* const* d_in, const int* in_sizes, int n_in,
                              void* d_out, int out_size, void* d_ws, size_t ws_size,
                              hipStream_t stream) {
    const void* V    = d_in[0];
    const void* Se   = d_in[1];
    const void* Si   = d_in[2];
    const void* Ce   = d_in[3];
    const void* Ci   = d_in[4];
    const void* Ksyn = d_in[5];
    const void* tau  = d_in[6];
    const void* dly  = d_in[7];
    const void* encb = d_in[8];
    const void* W1   = d_in[9];
    const void* b1   = d_in[10];
    const void* a1   = d_in[11];
    const void* W2   = d_in[12];
    const void* b2   = d_in[13];
    const void* a2   = d_in[14];
    const void* W3   = d_in[15];
    const void* b3   = d_in[16];
    const void* a3   = d_in[17];
    const void* W4   = d_in[18];
    const void* b4   = d_in[19];

    char* w = (char*)d_ws;
    float* ker_e = (float*)(w + OFF_KERE);
    float* ker_i = (float*)(w + OFF_KERI);
    int* ass_e   = (int*)(w + OFF_ASSE);
    int* ass_i   = (int*)(w + OFF_ASSI);
    unsigned short* W1h = (unsigned short*)(w + OFF_W1H);
    unsigned short* W1l = (unsigned short*)(w + OFF_W1L);
    unsigned short* W2h = (unsigned short*)(w + OFF_W2H);
    unsigned short* W2l = (unsigned short*)(w + OFF_W2L);
    unsigned short* W3h = (unsigned short*)(w + OFF_W3H);
    unsigned short* W3l = (unsigned short*)(w + OFF_W3L);
    unsigned short* W4h = (unsigned short*)(w + OFF_W4H);
    unsigned short* W4l = (unsigned short*)(w + OFF_W4L);
    unsigned char* in_e = (unsigned char*)(w + OFF_INE);
    unsigned char* in_i = (unsigned char*)(w + OFF_INI);
    float* S_conv = (float*)(w + OFF_SCONV);

    k_setup<<<722, 256, 0, stream>>>(Se, Ksyn, tau, dly, Ce, Ci, W1, W2, W3, W4,
                                     ker_e, ker_i, ass_e, ass_i,
                                     W1h, W1l, W2h, W2l, W3h, W3l, W4h, W4l);
    k_spikes<<<5000, 256, 0, stream>>>(Se, Si, ass_e, ass_i, in_e, in_i);
    k_conv<<<313, 256, 0, stream>>>(in_e, in_i, ker_e, ker_i, S_conv);
    k_mlp<<<625, 256, 0, stream>>>(Se, V, W1h, W1l, b1, a1, W2h, W2l, b2, a2,
                                   W3h, W3l, b3, a3, W4h, W4l, b4,
                                   encb, S_conv, d_out);
}

// Round 5
// 392.443 us; speedup vs baseline: 1.5080x; 1.0589x over previous
//
#include <hip/hip_runtime.h>
#include <cstdint>
#include <cstddef>

#define T_DATA 20000
#define E_NO 2000
#define I_NO 500
#define SUB_NO 16
#define HID 256
#define T_SYN 200
#define T_ENC 80
#define W_IN 159   // 2*T_ENC-1

typedef __attribute__((ext_vector_type(8))) __bf16 bf16x8;
typedef __attribute__((ext_vector_type(8))) short short8;
typedef __attribute__((ext_vector_type(4))) float floatx4;
typedef __attribute__((ext_vector_type(4))) unsigned int uint4v;
typedef __attribute__((ext_vector_type(2))) unsigned int uint2v;

__device__ __forceinline__ float bf2f(unsigned short u) {
    union { unsigned int i; float f; } v; v.i = ((unsigned int)u) << 16; return v.f;
}
__device__ __forceinline__ unsigned short f2bf(float f) {
    union { float f; unsigned int i; } v; v.f = f;
    unsigned int r = v.i + 0x7FFFu + ((v.i >> 16) & 1u);
    return (unsigned short)(r >> 16);
}
__device__ __forceinline__ float inload(const void* p, int i, int isbf) {
    return isbf ? bf2f(((const unsigned short*)p)[i]) : ((const float*)p)[i];
}

// per-block dtype detection: scan first 1024 u32 words of S_e (4 KB, L2-hot).
__device__ __forceinline__ int detect_bf(const void* Se, int* sfl) {
    if (threadIdx.x == 0) *sfl = 0;
    __syncthreads();
    const unsigned int* w = (const unsigned int*)Se;
    int la = 0;
    #pragma unroll
    for (int i = 0; i < 4; i++)
        la |= (w[i * 256 + threadIdx.x] & 0xFFFFu) ? 1 : 0;
    if (la) atomicOr(sfl, 1);
    __syncthreads();
    return *sfl;
}

// ---------------- ws layout (bytes, all 16B aligned) ----------------
#define OFF_KERE   16u        // 16*200 f32
#define OFF_KERI   12816u
#define OFF_SHE    25616u     // 2000 u8 (subunit*8 per e-synapse)
#define OFF_SHI    33616u     // 500 u8
#define OFF_W1H    35616u     // 256*160 bf16
#define OFF_W1L    117536u
#define OFF_W2H    199456u    // 256*256 bf16
#define OFF_W2L    330528u
#define OFF_W3H    461600u
#define OFF_W3L    592672u
#define OFF_W4H    723744u    // 15*256 bf16
#define OFF_W4L    731424u
#define OFF_INE    739104u    // 20000*16 u8
#define OFF_INI    1059104u
#define OFF_SCONV  1379104u   // 20000*16 f32 ; total 2659104 bytes

// ================= kernel 1: setup =================
__global__ void k_setup(const void* Se, const void* Ksyn, const void* tau_syn, const void* dly,
                        const void* Ce, const void* Ci,
                        const void* W1, const void* W2, const void* W3, const void* W4,
                        float* ker_e, float* ker_i, unsigned char* sh_e, unsigned char* sh_i,
                        unsigned short* W1h, unsigned short* W1l,
                        unsigned short* W2h, unsigned short* W2l,
                        unsigned short* W3h, unsigned short* W3l,
                        unsigned short* W4h, unsigned short* W4l) {
    __shared__ int sfl;
    int f = detect_bf(Se, &sfl);
    int id = blockIdx.x * 256 + threadIdx.x;
    if (id < 6400) {
        int c = id < 3200 ? 0 : 1;
        int q = id - c * 3200;
        int s = q / 200, j = q - s * 200;
        float d = expf(inload(dly, s * 2 + c, f));
        float tt = fmaxf((float)j - d, 0.0f);
        float acc = 0.f;
        #pragma unroll
        for (int b = 0; b < 3; b++) {
            float tau = expf(inload(tau_syn, b * 3 + c, f));
            float x = tt / tau;
            acc += x * expf(-x) * inload(Ksyn, (s * 3 + b) * 3 + c, f);
        }
        (c == 0 ? ker_e : ker_i)[s * 200 + j] = acc;
    } else if (id < 8400) {
        int e = id - 6400;
        int a = 0;
        for (int s = 0; s < 16; s++) if (inload(Ce, s * E_NO + e, f) > 0.5f) a = s;
        sh_e[e] = (unsigned char)(a * 8);
    } else if (id < 8900) {
        int e = id - 8400;
        int a = 0;
        for (int s = 0; s < 16; s++) if (inload(Ci, s * I_NO + e, f) > 0.5f) a = s;
        sh_i[e] = (unsigned char)(a * 8);
    } else if (id < 49860) {          // W1 pad 159->160 + hi/lo split
        int q = id - 8900;
        int n = q / 160, k = q - n * 160;
        float v = (k < W_IN) ? inload(W1, n * W_IN + k, f) : 0.f;
        unsigned short hi = f2bf(v);
        W1h[q] = hi;
        W1l[q] = f2bf(v - bf2f(hi));
    } else if (id < 115396) {         // W2 hi/lo
        int q = id - 49860;
        float v = inload(W2, q, f);
        unsigned short hi = f2bf(v);
        W2h[q] = hi;
        W2l[q] = f2bf(v - bf2f(hi));
    } else if (id < 180932) {         // W3 hi/lo
        int q = id - 115396;
        float v = inload(W3, q, f);
        unsigned short hi = f2bf(v);
        W3h[q] = hi;
        W3l[q] = f2bf(v - bf2f(hi));
    } else if (id < 184772) {         // W4 hi/lo
        int q = id - 180932;
        float v = inload(W4, q, f);
        unsigned short hi = f2bf(v);
        W4h[q] = hi;
        W4l[q] = f2bf(v - bf2f(hi));
    }
}

// ============ kernel 2: spike -> subunit counts (u8), BRANCHLESS ============
// wave = one t-row. Shift tables (subunit*8) staged in LDS; per spike slot:
// bit-extract + two masked 64-bit shifted adds. No branches, no L1 gathers.
__device__ __forceinline__ void acc_slot(unsigned int b, unsigned int sh,
                                         unsigned long long& lo, unsigned long long& hi) {
    unsigned int up = sh >> 6;            // 1 if subunit >= 8
    unsigned int s6 = sh & 63;
    lo += (unsigned long long)(b & (up ^ 1u)) << s6;
    hi += (unsigned long long)(b & up) << s6;
}

__global__ void __launch_bounds__(256) k_spikes(const void* Se, const void* Si,
                         const unsigned char* sh_e, const unsigned char* sh_i,
                         unsigned char* in_e, unsigned char* in_i) {
    __shared__ int sfl;
    __shared__ __align__(8) unsigned char she[E_NO];
    __shared__ __align__(8) unsigned char shi[I_NO];
    for (int i = threadIdx.x; i < E_NO / 4; i += 256)
        ((unsigned int*)she)[i] = ((const unsigned int*)sh_e)[i];
    for (int i = threadIdx.x; i < I_NO / 4; i += 256)
        ((unsigned int*)shi)[i] = ((const unsigned int*)sh_i)[i];
    int f = detect_bf(Se, &sfl);   // its syncthreads also covers table staging
    int lane = threadIdx.x & 63;
    int wave = threadIdx.x >> 6;
    int t = blockIdx.x * 4 + wave;
    unsigned long long e0 = 0, e1 = 0, i0 = 0, i1 = 0;
    if (f) {  // bf16: Se row = 250 x 16B (8 elems), Si row = 125 x 8B (4 elems)
        const uint4v* re = (const uint4v*)((const unsigned short*)Se + (size_t)t * E_NO);
        #pragma unroll
        for (int it = 0; it < 4; it++) {
            int c = it * 64 + lane;
            if (c < 250) {
                uint4v v = re[c];
                unsigned long long q = *(const unsigned long long*)&she[c * 8];
                #pragma unroll
                for (int w = 0; w < 4; w++) {
                    unsigned int x = v[w];
                    acc_slot((x >> 7) & 1u,  (unsigned int)(q >> (16 * w)) & 0xFFu, e0, e1);
                    acc_slot((x >> 23) & 1u, (unsigned int)(q >> (16 * w + 8)) & 0xFFu, e0, e1);
                }
            }
        }
        const uint2v* ri = (const uint2v*)((const unsigned short*)Si + (size_t)t * I_NO);
        #pragma unroll
        for (int it = 0; it < 2; it++) {
            int c = it * 64 + lane;
            if (c < 125) {
                uint2v v = ri[c];
                unsigned int q = *(const unsigned int*)&shi[c * 4];
                #pragma unroll
                for (int w = 0; w < 2; w++) {
                    unsigned int x = v[w];
                    acc_slot((x >> 7) & 1u,  (q >> (16 * w)) & 0xFFu, i0, i1);
                    acc_slot((x >> 23) & 1u, (q >> (16 * w + 8)) & 0xFFu, i0, i1);
                }
            }
        }
    } else {  // f32: test exponent bit 23 (1.0f = 0x3F800000)
        const uint4v* re = (const uint4v*)((const float*)Se + (size_t)t * E_NO);
        #pragma unroll
        for (int it = 0; it < 8; it++) {
            int c = it * 64 + lane;
            if (c < 500) {
                uint4v v = re[c];
                unsigned int q = *(const unsigned int*)&she[c * 4];
                #pragma unroll
                for (int w = 0; w < 4; w++)
                    acc_slot((v[w] >> 23) & 1u, (q >> (8 * w)) & 0xFFu, e0, e1);
            }
        }
        const uint2v* ri = (const uint2v*)((const float*)Si + (size_t)t * I_NO);
        #pragma unroll
        for (int it = 0; it < 4; it++) {
            int c = it * 64 + lane;
            if (c < 250) {
                uint2v v = ri[c];
                unsigned int q = *(const unsigned short*)&shi[c * 2];
                #pragma unroll
                for (int w = 0; w < 2; w++)
                    acc_slot((v[w] >> 23) & 1u, (q >> (8 * w)) & 0xFFu, i0, i1);
            }
        }
    }
    for (int off = 32; off; off >>= 1) {
        e0 += __shfl_xor(e0, off);
        e1 += __shfl_xor(e1, off);
        i0 += __shfl_xor(i0, off);
        i1 += __shfl_xor(i1, off);
    }
    if (lane < 16) {
        unsigned long long a = (lane < 8) ? e0 : e1;
        in_e[(size_t)t * 16 + lane] = (unsigned char)((a >> ((lane & 7) * 8)) & 0xFF);
    } else if (lane < 32) {
        int s = lane - 16;
        unsigned long long a = (s < 8) ? i0 : i1;
        in_i[(size_t)t * 16 + s] = (unsigned char)((a >> ((s & 7) * 8)) & 0xFF);
    }
}

// ============ kernel 3: causal conv, register sliding-window ============
__global__ void __launch_bounds__(256) k_conv(
        const unsigned char* in_e, const unsigned char* in_i,
        const float* ker_e, const float* ker_i, float* S_conv) {
    __shared__ float se[263 * 17];
    __shared__ float si[263 * 17];
    __shared__ float ke[16 * 201];
    __shared__ float ki[16 * 201];
    int t0 = blockIdx.x * 64;
    for (int idx = threadIdx.x; idx < 263 * 4; idx += 256) {
        int r = idx >> 2, wi = idx & 3;
        int t = t0 - 199 + r;
        unsigned int ve = 0, vi = 0;
        if (t >= 0 && t < T_DATA) {
            ve = ((const unsigned int*)in_e)[t * 4 + wi];
            vi = ((const unsigned int*)in_i)[t * 4 + wi];
        }
        #pragma unroll
        for (int b = 0; b < 4; b++) {
            se[r * 17 + wi * 4 + b] = (float)((ve >> (8 * b)) & 0xFF);
            si[r * 17 + wi * 4 + b] = (float)((vi >> (8 * b)) & 0xFF);
        }
    }
    for (int idx = threadIdx.x; idx < 3200; idx += 256) {
        int s = idx / 200, j = idx - s * 200;
        ke[s * 201 + j] = ker_e[idx];
        ki[s * 201 + j] = ker_i[idx];
    }
    __syncthreads();
    int s = threadIdx.x & 15, g4 = (threadIdx.x >> 4) * 4;
    float a0 = 0.f, a1 = 0.f, a2 = 0.f, a3 = 0.f;
    float w0 = se[(g4 + 199) * 17 + s], w1 = se[(g4 + 200) * 17 + s];
    float w2 = se[(g4 + 201) * 17 + s], w3 = se[(g4 + 202) * 17 + s];
    float x0 = si[(g4 + 199) * 17 + s], x1 = si[(g4 + 200) * 17 + s];
    float x2 = si[(g4 + 201) * 17 + s], x3 = si[(g4 + 202) * 17 + s];
    #pragma unroll 4
    for (int j = 0; j < 200; j++) {
        float kej = ke[s * 201 + j];
        float kij = ki[s * 201 + j];
        a0 += w0 * kej + x0 * kij;
        a1 += w1 * kej + x1 * kij;
        a2 += w2 * kej + x2 * kij;
        a3 += w3 * kej + x3 * kij;
        int lr = g4 + 198 - j; lr = lr < 0 ? 0 : lr;
        float nw = se[lr * 17 + s], nx = si[lr * 17 + s];
        w3 = w2; w2 = w1; w1 = w0; w0 = nw;
        x3 = x2; x2 = x1; x1 = x0; x0 = nx;
    }
    int tb = t0 + g4;
    if (tb + 0 < T_DATA) S_conv[(size_t)(tb + 0) * 16 + s] = a0;
    if (tb + 1 < T_DATA) S_conv[(size_t)(tb + 1) * 16 + s] = a1;
    if (tb + 2 < T_DATA) S_conv[(size_t)(tb + 2) * 16 + s] = a2;
    if (tb + 3 < T_DATA) S_conv[(size_t)(tb + 3) * 16 + s] = a3;
}

// ============ kernel 4: fused sliding-window MLP (unchanged from r4) ============
template<bool BF>
__device__ __forceinline__ void mlp_body(
    const void* V,
    const unsigned short* W1h, const unsigned short* W1l, const void* b1, const void* a1p,
    const unsigned short* W2h, const unsigned short* W2l, const void* b2, const void* a2p,
    const unsigned short* W3h, const unsigned short* W3l, const void* b3, const void* a3p,
    const unsigned short* W4h, const unsigned short* W4l, const void* b4,
    const void* encb, const float* S_conv, void* out,
    unsigned short* Ahi, unsigned short* Alo)
{
    int tid = threadIdx.x;
    int lane = tid & 63, wave = tid >> 6;
    int lm = lane & 15, quad = lane >> 4;
    int t0 = blockIdx.x * 32;

    auto ld = [&](const void* p, int i) -> float {
        return BF ? bf2f(((const unsigned short*)p)[i]) : ((const float*)p)[i];
    };

    for (int idx = tid; idx < 32 * 160; idx += 256) {
        int m = idx / 160, k = idx - m * 160;
        int tg = t0 + m + k - (T_ENC - 1);
        float v = 0.f;
        if (k < W_IN && tg >= 0 && tg < T_DATA) v = ld(V, tg);
        unsigned short hi = f2bf(v);
        int col = (((k >> 3) ^ m) << 3) | (k & 7);
        Ahi[m * 256 + col] = hi;
        Alo[m * 256 + col] = f2bf(v - bf2f(hi));
    }
    __syncthreads();

    floatx4 acc[2][4];
    auto aoff = [&](int mt, int ks) {
        int arow = mt * 16 + lm;
        return arow * 256 + ((((ks << 2) | quad) ^ arow) << 3);
    };

    auto epi = [&](const void* bias, float alpha) {
        __syncthreads();
        #pragma unroll
        for (int mt = 0; mt < 2; mt++) {
            #pragma unroll
            for (int nt = 0; nt < 4; nt++) {
                int cn = wave * 64 + nt * 16 + lm;
                float bb = ld(bias, cn);
                #pragma unroll
                for (int j = 0; j < 4; j++) {
                    int row = mt * 16 + quad * 4 + j;
                    float h = acc[mt][nt][j] + bb;
                    h = (h >= 0.f) ? h : alpha * h;
                    unsigned short hi = f2bf(h);
                    int col = (((cn >> 3) ^ row) << 3) | (cn & 7);
                    Ahi[row * 256 + col] = hi;
                    Alo[row * 256 + col] = f2bf(h - bf2f(hi));
                }
            }
        }
        __syncthreads();
    };

    floatx4 z = {0.f, 0.f, 0.f, 0.f};
    {
        #pragma unroll
        for (int mt = 0; mt < 2; mt++)
            #pragma unroll
            for (int nt = 0; nt < 4; nt++) acc[mt][nt] = z;
        #pragma unroll
        for (int ks = 0; ks < 5; ks++) {
            bf16x8 ah0 = *(const bf16x8*)&Ahi[aoff(0, ks)];
            bf16x8 ah1 = *(const bf16x8*)&Ahi[aoff(1, ks)];
            bf16x8 al0, al1;
            if (!BF) { al0 = *(const bf16x8*)&Alo[aoff(0, ks)];
                       al1 = *(const bf16x8*)&Alo[aoff(1, ks)]; }
            #pragma unroll
            for (int nt = 0; nt < 4; nt++) {
                int cn = wave * 64 + nt * 16 + lm;
                size_t bo = (size_t)cn * 160 + ks * 32 + quad * 8;
                bf16x8 bh = *(const bf16x8*)(W1h + bo);
                acc[0][nt] = __builtin_amdgcn_mfma_f32_16x16x32_bf16(ah0, bh, acc[0][nt], 0, 0, 0);
                acc[1][nt] = __builtin_amdgcn_mfma_f32_16x16x32_bf16(ah1, bh, acc[1][nt], 0, 0, 0);
                if (!BF) {
                    bf16x8 bl = *(const bf16x8*)(W1l + bo);
                    acc[0][nt] = __builtin_amdgcn_mfma_f32_16x16x32_bf16(al0, bh, acc[0][nt], 0, 0, 0);
                    acc[1][nt] = __builtin_amdgcn_mfma_f32_16x16x32_bf16(al1, bh, acc[1][nt], 0, 0, 0);
                    acc[0][nt] = __builtin_amdgcn_mfma_f32_16x16x32_bf16(ah0, bl, acc[0][nt], 0, 0, 0);
                    acc[1][nt] = __builtin_amdgcn_mfma_f32_16x16x32_bf16(ah1, bl, acc[1][nt], 0, 0, 0);
                }
            }
        }
        epi(b1, ld(a1p, 0));
    }
    const unsigned short* Whs[2] = {W2h, W3h};
    const unsigned short* Wls[2] = {W2l, W3l};
    const void* bs[2] = {b2, b3};
    const void* as_[2] = {a2p, a3p};
    for (int l = 0; l < 2; l++) {
        #pragma unroll
        for (int mt = 0; mt < 2; mt++)
            #pragma unroll
            for (int nt = 0; nt < 4; nt++) acc[mt][nt] = z;
        const unsigned short* Wh = Whs[l];
        const unsigned short* Wl = Wls[l];
        #pragma unroll
        for (int ks = 0; ks < 8; ks++) {
            bf16x8 ah0 = *(const bf16x8*)&Ahi[aoff(0, ks)];
            bf16x8 ah1 = *(const bf16x8*)&Ahi[aoff(1, ks)];
            bf16x8 al0 = *(const bf16x8*)&Alo[aoff(0, ks)];
            bf16x8 al1 = *(const bf16x8*)&Alo[aoff(1, ks)];
            #pragma unroll
            for (int nt = 0; nt < 4; nt++) {
                int cn = wave * 64 + nt * 16 + lm;
                size_t bo = (size_t)cn * 256 + ks * 32 + quad * 8;
                bf16x8 bh = *(const bf16x8*)(Wh + bo);
                acc[0][nt] = __builtin_amdgcn_mfma_f32_16x16x32_bf16(ah0, bh, acc[0][nt], 0, 0, 0);
                acc[1][nt] = __builtin_amdgcn_mfma_f32_16x16x32_bf16(ah1, bh, acc[1][nt], 0, 0, 0);
                acc[0][nt] = __builtin_amdgcn_mfma_f32_16x16x32_bf16(al0, bh, acc[0][nt], 0, 0, 0);
                acc[1][nt] = __builtin_amdgcn_mfma_f32_16x16x32_bf16(al1, bh, acc[1][nt], 0, 0, 0);
                if (!BF) {
                    bf16x8 bl = *(const bf16x8*)(Wl + bo);
                    acc[0][nt] = __builtin_amdgcn_mfma_f32_16x16x32_bf16(ah0, bl, acc[0][nt], 0, 0, 0);
                    acc[1][nt] = __builtin_amdgcn_mfma_f32_16x16x32_bf16(ah1, bl, acc[1][nt], 0, 0, 0);
                }
            }
        }
        epi(bs[l], ld(as_[l], 0));
    }
    if (wave < 2) {
        int mt = wave;
        short8 z8 = {0, 0, 0, 0, 0, 0, 0, 0};
        bf16x8 bz = __builtin_bit_cast(bf16x8, z8);
        floatx4 a4 = z;
        #pragma unroll
        for (int ks = 0; ks < 8; ks++) {
            bf16x8 ah = *(const bf16x8*)&Ahi[aoff(mt, ks)];
            bf16x8 al = *(const bf16x8*)&Alo[aoff(mt, ks)];
            bf16x8 bh = bz, bl = bz;
            if (lm < 15) {
                size_t bo = (size_t)lm * 256 + ks * 32 + quad * 8;
                bh = *(const bf16x8*)(W4h + bo);
                if (!BF) bl = *(const bf16x8*)(W4l + bo);
            }
            a4 = __builtin_amdgcn_mfma_f32_16x16x32_bf16(ah, bh, a4, 0, 0, 0);
            a4 = __builtin_amdgcn_mfma_f32_16x16x32_bf16(al, bh, a4, 0, 0, 0);
            if (!BF)
                a4 = __builtin_amdgcn_mfma_f32_16x16x32_bf16(ah, bl, a4, 0, 0, 0);
        }
        if (lm < 15) {
            float bb = ld(b4, lm) + ld(encb, lm);
            #pragma unroll
            for (int j = 0; j < 4; j++) {
                int row = mt * 16 + quad * 4 + j;
                int t = t0 + row;
                float x = a4[j] + bb + S_conv[(size_t)t * 16 + lm + 1];
                x = fminf(fmaxf(x, -40.f), 40.f);
                float sg = 1.f / (1.f + expf(-x));
                if (BF) ((unsigned short*)out)[(size_t)t * 15 + lm] = f2bf(sg);
                else    ((float*)out)[(size_t)t * 15 + lm] = sg;
            }
        }
    }
}

__global__ void __launch_bounds__(256) k_mlp(
    const void* Se, const void* V,
    const unsigned short* W1h, const unsigned short* W1l, const void* b1, const void* a1p,
    const unsigned short* W2h, const unsigned short* W2l, const void* b2, const void* a2p,
    const unsigned short* W3h, const unsigned short* W3l, const void* b3, const void* a3p,
    const unsigned short* W4h, const unsigned short* W4l, const void* b4,
    const void* encb, const float* S_conv, void* out) {
    __shared__ __align__(16) unsigned short Ahi[32 * 256];
    __shared__ __align__(16) unsigned short Alo[32 * 256];
    __shared__ int sfl;
    int f = detect_bf(Se, &sfl);
    if (f)
        mlp_body<true>(V, W1h, W1l, b1, a1p, W2h, W2l, b2, a2p, W3h, W3l, b3, a3p,
                       W4h, W4l, b4, encb, S_conv, out, Ahi, Alo);
    else
        mlp_body<false>(V, W1h, W1l, b1, a1p, W2h, W2l, b2, a2p, W3h, W3l, b3, a3p,
                        W4h, W4l, b4, encb, S_conv, out, Ahi, Alo);
}

extern "C" void kernel_launch(void* const* d_in, const int* in_sizes, int n_in,
                              void* d_out, int out_size, void* d_ws, size_t ws_size,
                              hipStream_t stream) {
    const void* V    = d_in[0];
    const void* Se   = d_in[1];
    const void* Si   = d_in[2];
    const void* Ce   = d_in[3];
    const void* Ci   = d_in[4];
    const void* Ksyn = d_in[5];
    const void* tau  = d_in[6];
    const void* dly  = d_in[7];
    const void* encb = d_in[8];
    const void* W1   = d_in[9];
    const void* b1   = d_in[10];
    const void* a1   = d_in[11];
    const void* W2   = d_in[12];
    const void* b2   = d_in[13];
    const void* a2   = d_in[14];
    const void* W3   = d_in[15];
    const void* b3   = d_in[16];
    const void* a3   = d_in[17];
    const void* W4   = d_in[18];
    const void* b4   = d_in[19];

    char* w = (char*)d_ws;
    float* ker_e = (float*)(w + OFF_KERE);
    float* ker_i = (float*)(w + OFF_KERI);
    unsigned char* sh_e = (unsigned char*)(w + OFF_SHE);
    unsigned char* sh_i = (unsigned char*)(w + OFF_SHI);
    unsigned short* W1h = (unsigned short*)(w + OFF_W1H);
    unsigned short* W1l = (unsigned short*)(w + OFF_W1L);
    unsigned short* W2h = (unsigned short*)(w + OFF_W2H);
    unsigned short* W2l = (unsigned short*)(w + OFF_W2L);
    unsigned short* W3h = (unsigned short*)(w + OFF_W3H);
    unsigned short* W3l = (unsigned short*)(w + OFF_W3L);
    unsigned short* W4h = (unsigned short*)(w + OFF_W4H);
    unsigned short* W4l = (unsigned short*)(w + OFF_W4L);
    unsigned char* in_e = (unsigned char*)(w + OFF_INE);
    unsigned char* in_i = (unsigned char*)(w + OFF_INI);
    float* S_conv = (float*)(w + OFF_SCONV);

    k_setup<<<722, 256, 0, stream>>>(Se, Ksyn, tau, dly, Ce, Ci, W1, W2, W3, W4,
                                     ker_e, ker_i, sh_e, sh_i,
                                     W1h, W1l, W2h, W2l, W3h, W3l, W4h, W4l);
    k_spikes<<<5000, 256, 0, stream>>>(Se, Si, sh_e, sh_i, in_e, in_i);
    k_conv<<<313, 256, 0, stream>>>(in_e, in_i, ker_e, ker_i, S_conv);
    k_mlp<<<625, 256, 0, stream>>>(Se, V, W1h, W1l, b1, a1, W2h, W2l, b2, a2,
                                   W3h, W3l, b3, a3, W4h, W4l, b4,
                                   encb, S_conv, d_out);
}

// Round 6
// 373.243 us; speedup vs baseline: 1.5855x; 1.0514x over previous
//
#include <hip/hip_runtime.h>
#include <cstdint>
#include <cstddef>

#define T_DATA 20000
#define E_NO 2000
#define I_NO 500
#define SUB_NO 16
#define HID 256
#define T_SYN 200
#define T_ENC 80
#define W_IN 159   // 2*T_ENC-1

typedef __attribute__((ext_vector_type(8))) __bf16 bf16x8;
typedef __attribute__((ext_vector_type(8))) short short8;
typedef __attribute__((ext_vector_type(4))) float floatx4;
typedef __attribute__((ext_vector_type(4))) unsigned int uint4v;
typedef __attribute__((ext_vector_type(2))) unsigned int uint2v;

__device__ __forceinline__ float bf2f(unsigned short u) {
    union { unsigned int i; float f; } v; v.i = ((unsigned int)u) << 16; return v.f;
}
__device__ __forceinline__ unsigned short f2bf(float f) {
    union { float f; unsigned int i; } v; v.f = f;
    unsigned int r = v.i + 0x7FFFu + ((v.i >> 16) & 1u);
    return (unsigned short)(r >> 16);
}
__device__ __forceinline__ float inload(const void* p, int i, int isbf) {
    return isbf ? bf2f(((const unsigned short*)p)[i]) : ((const float*)p)[i];
}

// per-block dtype detection: scan first 1024 u32 words of S_e (4 KB, L2-hot).
__device__ __forceinline__ int detect_bf(const void* Se, int* sfl) {
    if (threadIdx.x == 0) *sfl = 0;
    __syncthreads();
    const unsigned int* w = (const unsigned int*)Se;
    int la = 0;
    #pragma unroll
    for (int i = 0; i < 4; i++)
        la |= (w[i * 256 + threadIdx.x] & 0xFFFFu) ? 1 : 0;
    if (la) atomicOr(sfl, 1);
    __syncthreads();
    return *sfl;
}

// ---------------- ws layout (bytes, all 16B aligned) ----------------
#define OFF_KERE   16u        // 16*200 f32
#define OFF_KERI   12816u
#define OFF_SHE    25616u     // 2000 u8 (subunit*8 per e-synapse)
#define OFF_SHI    33616u     // 500 u8
#define OFF_W1H    35616u     // 256*160 bf16
#define OFF_W1L    117536u
#define OFF_W2H    199456u    // 256*256 bf16
#define OFF_W2L    330528u
#define OFF_W3H    461600u
#define OFF_W3L    592672u
#define OFF_W4H    723744u    // 15*256 bf16
#define OFF_W4L    731424u
#define OFF_INE    739104u    // 20000*16 u8
#define OFF_INI    1059104u
#define OFF_SCONV  1379104u   // 20000*16 f32 ; total 2659104 bytes

// ================= kernel 1: setup =================
__global__ void k_setup(const void* Se, const void* Ksyn, const void* tau_syn, const void* dly,
                        const void* Ce, const void* Ci,
                        const void* W1, const void* W2, const void* W3, const void* W4,
                        float* ker_e, float* ker_i, unsigned char* sh_e, unsigned char* sh_i,
                        unsigned short* W1h, unsigned short* W1l,
                        unsigned short* W2h, unsigned short* W2l,
                        unsigned short* W3h, unsigned short* W3l,
                        unsigned short* W4h, unsigned short* W4l) {
    __shared__ int sfl;
    int f = detect_bf(Se, &sfl);
    int id = blockIdx.x * 256 + threadIdx.x;
    if (id < 6400) {
        int c = id < 3200 ? 0 : 1;
        int q = id - c * 3200;
        int s = q / 200, j = q - s * 200;
        float d = expf(inload(dly, s * 2 + c, f));
        float tt = fmaxf((float)j - d, 0.0f);
        float acc = 0.f;
        #pragma unroll
        for (int b = 0; b < 3; b++) {
            float tau = expf(inload(tau_syn, b * 3 + c, f));
            float x = tt / tau;
            acc += x * expf(-x) * inload(Ksyn, (s * 3 + b) * 3 + c, f);
        }
        (c == 0 ? ker_e : ker_i)[s * 200 + j] = acc;
    } else if (id < 8400) {
        int e = id - 6400;
        int a = 0;
        for (int s = 0; s < 16; s++) if (inload(Ce, s * E_NO + e, f) > 0.5f) a = s;
        sh_e[e] = (unsigned char)(a * 8);
    } else if (id < 8900) {
        int e = id - 8400;
        int a = 0;
        for (int s = 0; s < 16; s++) if (inload(Ci, s * I_NO + e, f) > 0.5f) a = s;
        sh_i[e] = (unsigned char)(a * 8);
    } else if (id < 49860) {          // W1 pad 159->160 + hi/lo split
        int q = id - 8900;
        int n = q / 160, k = q - n * 160;
        float v = (k < W_IN) ? inload(W1, n * W_IN + k, f) : 0.f;
        unsigned short hi = f2bf(v);
        W1h[q] = hi;
        W1l[q] = f2bf(v - bf2f(hi));
    } else if (id < 115396) {         // W2 hi/lo
        int q = id - 49860;
        float v = inload(W2, q, f);
        unsigned short hi = f2bf(v);
        W2h[q] = hi;
        W2l[q] = f2bf(v - bf2f(hi));
    } else if (id < 180932) {         // W3 hi/lo
        int q = id - 115396;
        float v = inload(W3, q, f);
        unsigned short hi = f2bf(v);
        W3h[q] = hi;
        W3l[q] = f2bf(v - bf2f(hi));
    } else if (id < 184772) {         // W4 hi/lo
        int q = id - 180932;
        float v = inload(W4, q, f);
        unsigned short hi = f2bf(v);
        W4h[q] = hi;
        W4l[q] = f2bf(v - bf2f(hi));
    }
}

// ============ kernel 2: spike -> subunit counts (u8), BRANCHLESS ============
__device__ __forceinline__ void acc_slot(unsigned int b, unsigned int sh,
                                         unsigned long long& lo, unsigned long long& hi) {
    unsigned int up = sh >> 6;            // 1 if subunit >= 8
    unsigned int s6 = sh & 63;
    lo += (unsigned long long)(b & (up ^ 1u)) << s6;
    hi += (unsigned long long)(b & up) << s6;
}

__global__ void __launch_bounds__(256) k_spikes(const void* Se, const void* Si,
                         const unsigned char* sh_e, const unsigned char* sh_i,
                         unsigned char* in_e, unsigned char* in_i) {
    __shared__ int sfl;
    __shared__ __align__(8) unsigned char she[E_NO];
    __shared__ __align__(8) unsigned char shi[I_NO];
    for (int i = threadIdx.x; i < E_NO / 4; i += 256)
        ((unsigned int*)she)[i] = ((const unsigned int*)sh_e)[i];
    for (int i = threadIdx.x; i < I_NO / 4; i += 256)
        ((unsigned int*)shi)[i] = ((const unsigned int*)sh_i)[i];
    int f = detect_bf(Se, &sfl);   // its syncthreads also covers table staging
    int lane = threadIdx.x & 63;
    int wave = threadIdx.x >> 6;
    int t = blockIdx.x * 4 + wave;
    unsigned long long e0 = 0, e1 = 0, i0 = 0, i1 = 0;
    if (f) {
        const uint4v* re = (const uint4v*)((const unsigned short*)Se + (size_t)t * E_NO);
        #pragma unroll
        for (int it = 0; it < 4; it++) {
            int c = it * 64 + lane;
            if (c < 250) {
                uint4v v = re[c];
                unsigned long long q = *(const unsigned long long*)&she[c * 8];
                #pragma unroll
                for (int w = 0; w < 4; w++) {
                    unsigned int x = v[w];
                    acc_slot((x >> 7) & 1u,  (unsigned int)(q >> (16 * w)) & 0xFFu, e0, e1);
                    acc_slot((x >> 23) & 1u, (unsigned int)(q >> (16 * w + 8)) & 0xFFu, e0, e1);
                }
            }
        }
        const uint2v* ri = (const uint2v*)((const unsigned short*)Si + (size_t)t * I_NO);
        #pragma unroll
        for (int it = 0; it < 2; it++) {
            int c = it * 64 + lane;
            if (c < 125) {
                uint2v v = ri[c];
                unsigned int q = *(const unsigned int*)&shi[c * 4];
                #pragma unroll
                for (int w = 0; w < 2; w++) {
                    unsigned int x = v[w];
                    acc_slot((x >> 7) & 1u,  (q >> (16 * w)) & 0xFFu, i0, i1);
                    acc_slot((x >> 23) & 1u, (q >> (16 * w + 8)) & 0xFFu, i0, i1);
                }
            }
        }
    } else {
        const uint4v* re = (const uint4v*)((const float*)Se + (size_t)t * E_NO);
        #pragma unroll
        for (int it = 0; it < 8; it++) {
            int c = it * 64 + lane;
            if (c < 500) {
                uint4v v = re[c];
                unsigned int q = *(const unsigned int*)&she[c * 4];
                #pragma unroll
                for (int w = 0; w < 4; w++)
                    acc_slot((v[w] >> 23) & 1u, (q >> (8 * w)) & 0xFFu, e0, e1);
            }
        }
        const uint2v* ri = (const uint2v*)((const float*)Si + (size_t)t * I_NO);
        #pragma unroll
        for (int it = 0; it < 4; it++) {
            int c = it * 64 + lane;
            if (c < 250) {
                uint2v v = ri[c];
                unsigned int q = *(const unsigned short*)&shi[c * 2];
                #pragma unroll
                for (int w = 0; w < 2; w++)
                    acc_slot((v[w] >> 23) & 1u, (q >> (8 * w)) & 0xFFu, i0, i1);
            }
        }
    }
    for (int off = 32; off; off >>= 1) {
        e0 += __shfl_xor(e0, off);
        e1 += __shfl_xor(e1, off);
        i0 += __shfl_xor(i0, off);
        i1 += __shfl_xor(i1, off);
    }
    if (lane < 16) {
        unsigned long long a = (lane < 8) ? e0 : e1;
        in_e[(size_t)t * 16 + lane] = (unsigned char)((a >> ((lane & 7) * 8)) & 0xFF);
    } else if (lane < 32) {
        int s = lane - 16;
        unsigned long long a = (s < 8) ? i0 : i1;
        in_i[(size_t)t * 16 + s] = (unsigned char)((a >> ((s & 7) * 8)) & 0xFF);
    }
}

// ============ kernel 3: causal conv, register sliding-window ============
__global__ void __launch_bounds__(256) k_conv(
        const unsigned char* in_e, const unsigned char* in_i,
        const float* ker_e, const float* ker_i, float* S_conv) {
    __shared__ float se[263 * 17];
    __shared__ float si[263 * 17];
    __shared__ float ke[16 * 201];
    __shared__ float ki[16 * 201];
    int t0 = blockIdx.x * 64;
    for (int idx = threadIdx.x; idx < 263 * 4; idx += 256) {
        int r = idx >> 2, wi = idx & 3;
        int t = t0 - 199 + r;
        unsigned int ve = 0, vi = 0;
        if (t >= 0 && t < T_DATA) {
            ve = ((const unsigned int*)in_e)[t * 4 + wi];
            vi = ((const unsigned int*)in_i)[t * 4 + wi];
        }
        #pragma unroll
        for (int b = 0; b < 4; b++) {
            se[r * 17 + wi * 4 + b] = (float)((ve >> (8 * b)) & 0xFF);
            si[r * 17 + wi * 4 + b] = (float)((vi >> (8 * b)) & 0xFF);
        }
    }
    for (int idx = threadIdx.x; idx < 3200; idx += 256) {
        int s = idx / 200, j = idx - s * 200;
        ke[s * 201 + j] = ker_e[idx];
        ki[s * 201 + j] = ker_i[idx];
    }
    __syncthreads();
    int s = threadIdx.x & 15, g4 = (threadIdx.x >> 4) * 4;
    float a0 = 0.f, a1 = 0.f, a2 = 0.f, a3 = 0.f;
    float w0 = se[(g4 + 199) * 17 + s], w1 = se[(g4 + 200) * 17 + s];
    float w2 = se[(g4 + 201) * 17 + s], w3 = se[(g4 + 202) * 17 + s];
    float x0 = si[(g4 + 199) * 17 + s], x1 = si[(g4 + 200) * 17 + s];
    float x2 = si[(g4 + 201) * 17 + s], x3 = si[(g4 + 202) * 17 + s];
    #pragma unroll 4
    for (int j = 0; j < 200; j++) {
        float kej = ke[s * 201 + j];
        float kij = ki[s * 201 + j];
        a0 += w0 * kej + x0 * kij;
        a1 += w1 * kej + x1 * kij;
        a2 += w2 * kej + x2 * kij;
        a3 += w3 * kej + x3 * kij;
        int lr = g4 + 198 - j; lr = lr < 0 ? 0 : lr;
        float nw = se[lr * 17 + s], nx = si[lr * 17 + s];
        w3 = w2; w2 = w1; w1 = w0; w0 = nw;
        x3 = x2; x2 = x1; x1 = x0; x0 = nx;
    }
    int tb = t0 + g4;
    if (tb + 0 < T_DATA) S_conv[(size_t)(tb + 0) * 16 + s] = a0;
    if (tb + 1 < T_DATA) S_conv[(size_t)(tb + 1) * 16 + s] = a1;
    if (tb + 2 < T_DATA) S_conv[(size_t)(tb + 2) * 16 + s] = a2;
    if (tb + 3 < T_DATA) S_conv[(size_t)(tb + 3) * 16 + s] = a3;
}

// ============ kernel 4: fused sliding-window MLP, M=64, B-preload ============
// 64 t-rows/block, grid 313. 4 waves; wave w owns N-cols [64w,64w+64).
// BF mode: h carried as plain bf16 (no lo stream; adds ~1e-3 logit noise,
// budget 0.064) -> L2/L3 are 128 MFMAs/wave against a 32-frag (128 VGPR)
// register-preloaded weight slice: one ~500cyc L2 burst per layer instead of
// per-ks exposed latency. f32 fallback streams hi+lo (cold path).
template<bool BF>
__device__ __forceinline__ void mlp_body(
    const void* V,
    const unsigned short* W1h, const unsigned short* W1l, const void* b1, const void* a1p,
    const unsigned short* W2h, const unsigned short* W2l, const void* b2, const void* a2p,
    const unsigned short* W3h, const unsigned short* W3l, const void* b3, const void* a3p,
    const unsigned short* W4h, const unsigned short* W4l, const void* b4,
    const void* encb, const float* S_conv, void* out,
    unsigned short* Ahi, unsigned short* Alo)
{
    int tid = threadIdx.x;
    int lane = tid & 63, wave = tid >> 6;
    int lm = lane & 15, quad = lane >> 4;
    int t0 = blockIdx.x * 64;

    auto ld = [&](const void* p, int i) -> float {
        return BF ? bf2f(((const unsigned short*)p)[i]) : ((const float*)p)[i];
    };

    // stage layer-1 A: 64 rows x 160 cols, XOR kgroup swizzle (5-bit row mask)
    for (int idx = tid; idx < 64 * 160; idx += 256) {
        int m = idx / 160, k = idx - m * 160;
        int tg = t0 + m + k - (T_ENC - 1);
        float v = 0.f;
        if (k < W_IN && tg >= 0 && tg < T_DATA) v = ld(V, tg);
        unsigned short hi = f2bf(v);
        int col = (((k >> 3) ^ (m & 31)) << 3) | (k & 7);
        Ahi[m * 256 + col] = hi;
        if (!BF) Alo[m * 256 + col] = f2bf(v - bf2f(hi));
    }
    __syncthreads();

    floatx4 acc[4][4];   // [mt][nt]
    auto aoff = [&](int mt, int ks) {
        int arow = mt * 16 + lm;
        return arow * 256 + ((((ks << 2) | quad) ^ (arow & 31)) << 3);
    };

    auto epi = [&](const void* bias, float alpha) {
        __syncthreads();
        #pragma unroll
        for (int mt = 0; mt < 4; mt++) {
            #pragma unroll
            for (int nt = 0; nt < 4; nt++) {
                int cn = wave * 64 + nt * 16 + lm;
                float bb = ld(bias, cn);
                #pragma unroll
                for (int j = 0; j < 4; j++) {
                    int row = mt * 16 + quad * 4 + j;
                    float h = acc[mt][nt][j] + bb;
                    h = (h >= 0.f) ? h : alpha * h;
                    unsigned short hi = f2bf(h);
                    int col = (((cn >> 3) ^ (row & 31)) << 3) | (cn & 7);
                    Ahi[row * 256 + col] = hi;
                    if (!BF) Alo[row * 256 + col] = f2bf(h - bf2f(hi));
                }
            }
        }
        __syncthreads();
    };

    floatx4 z = {0.f, 0.f, 0.f, 0.f};
    // ---- layer 1: K=160 (5 ks) ----
    {
        #pragma unroll
        for (int mt = 0; mt < 4; mt++)
            #pragma unroll
            for (int nt = 0; nt < 4; nt++) acc[mt][nt] = z;
        if (BF) {
            bf16x8 Bh[5][4];
            #pragma unroll
            for (int ks = 0; ks < 5; ks++)
                #pragma unroll
                for (int nt = 0; nt < 4; nt++)
                    Bh[ks][nt] = *(const bf16x8*)(W1h + (size_t)(wave * 64 + nt * 16 + lm) * 160 + ks * 32 + quad * 8);
            #pragma unroll
            for (int ks = 0; ks < 5; ks++) {
                bf16x8 a[4];
                #pragma unroll
                for (int mt = 0; mt < 4; mt++) a[mt] = *(const bf16x8*)&Ahi[aoff(mt, ks)];
                #pragma unroll
                for (int nt = 0; nt < 4; nt++)
                    #pragma unroll
                    for (int mt = 0; mt < 4; mt++)
                        acc[mt][nt] = __builtin_amdgcn_mfma_f32_16x16x32_bf16(a[mt], Bh[ks][nt], acc[mt][nt], 0, 0, 0);
            }
        } else {
            for (int ks = 0; ks < 5; ks++) {
                bf16x8 ah[4], al[4];
                #pragma unroll
                for (int mt = 0; mt < 4; mt++) {
                    ah[mt] = *(const bf16x8*)&Ahi[aoff(mt, ks)];
                    al[mt] = *(const bf16x8*)&Alo[aoff(mt, ks)];
                }
                #pragma unroll
                for (int nt = 0; nt < 4; nt++) {
                    size_t bo = (size_t)(wave * 64 + nt * 16 + lm) * 160 + ks * 32 + quad * 8;
                    bf16x8 bh = *(const bf16x8*)(W1h + bo);
                    bf16x8 bl = *(const bf16x8*)(W1l + bo);
                    #pragma unroll
                    for (int mt = 0; mt < 4; mt++) {
                        acc[mt][nt] = __builtin_amdgcn_mfma_f32_16x16x32_bf16(ah[mt], bh, acc[mt][nt], 0, 0, 0);
                        acc[mt][nt] = __builtin_amdgcn_mfma_f32_16x16x32_bf16(al[mt], bh, acc[mt][nt], 0, 0, 0);
                        acc[mt][nt] = __builtin_amdgcn_mfma_f32_16x16x32_bf16(ah[mt], bl, acc[mt][nt], 0, 0, 0);
                    }
                }
            }
        }
        epi(b1, ld(a1p, 0));
    }
    // ---- layers 2,3: K=256 (8 ks) ----
    const unsigned short* Whs[2] = {W2h, W3h};
    const unsigned short* Wls[2] = {W2l, W3l};
    const void* bs[2] = {b2, b3};
    const void* as_[2] = {a2p, a3p};
    for (int l = 0; l < 2; l++) {
        #pragma unroll
        for (int mt = 0; mt < 4; mt++)
            #pragma unroll
            for (int nt = 0; nt < 4; nt++) acc[mt][nt] = z;
        const unsigned short* Wh = Whs[l];
        const unsigned short* Wl = Wls[l];
        if (BF) {
            bf16x8 Bh[8][4];   // full-layer weight slice in registers (128 VGPRs)
            #pragma unroll
            for (int ks = 0; ks < 8; ks++)
                #pragma unroll
                for (int nt = 0; nt < 4; nt++)
                    Bh[ks][nt] = *(const bf16x8*)(Wh + (size_t)(wave * 64 + nt * 16 + lm) * 256 + ks * 32 + quad * 8);
            #pragma unroll
            for (int ks = 0; ks < 8; ks++) {
                bf16x8 a[4];
                #pragma unroll
                for (int mt = 0; mt < 4; mt++) a[mt] = *(const bf16x8*)&Ahi[aoff(mt, ks)];
                #pragma unroll
                for (int nt = 0; nt < 4; nt++)
                    #pragma unroll
                    for (int mt = 0; mt < 4; mt++)
                        acc[mt][nt] = __builtin_amdgcn_mfma_f32_16x16x32_bf16(a[mt], Bh[ks][nt], acc[mt][nt], 0, 0, 0);
            }
        } else {
            for (int ks = 0; ks < 8; ks++) {
                bf16x8 ah[4], al[4];
                #pragma unroll
                for (int mt = 0; mt < 4; mt++) {
                    ah[mt] = *(const bf16x8*)&Ahi[aoff(mt, ks)];
                    al[mt] = *(const bf16x8*)&Alo[aoff(mt, ks)];
                }
                #pragma unroll
                for (int nt = 0; nt < 4; nt++) {
                    size_t bo = (size_t)(wave * 64 + nt * 16 + lm) * 256 + ks * 32 + quad * 8;
                    bf16x8 bh = *(const bf16x8*)(Wh + bo);
                    bf16x8 bl = *(const bf16x8*)(Wl + bo);
                    #pragma unroll
                    for (int mt = 0; mt < 4; mt++) {
                        acc[mt][nt] = __builtin_amdgcn_mfma_f32_16x16x32_bf16(ah[mt], bh, acc[mt][nt], 0, 0, 0);
                        acc[mt][nt] = __builtin_amdgcn_mfma_f32_16x16x32_bf16(al[mt], bh, acc[mt][nt], 0, 0, 0);
                        acc[mt][nt] = __builtin_amdgcn_mfma_f32_16x16x32_bf16(ah[mt], bl, acc[mt][nt], 0, 0, 0);
                    }
                }
            }
        }
        epi(bs[l], ld(as_[l], 0));
    }
    // ---- layer 4: N=15 (16-padded), wave takes M-tile mt=wave ----
    {
        int mt = wave;
        short8 z8 = {0, 0, 0, 0, 0, 0, 0, 0};
        bf16x8 bz = __builtin_bit_cast(bf16x8, z8);
        floatx4 a4 = z;
        #pragma unroll
        for (int ks = 0; ks < 8; ks++) {
            bf16x8 ah = *(const bf16x8*)&Ahi[aoff(mt, ks)];
            bf16x8 bh = bz;
            if (lm < 15)
                bh = *(const bf16x8*)(W4h + (size_t)lm * 256 + ks * 32 + quad * 8);
            a4 = __builtin_amdgcn_mfma_f32_16x16x32_bf16(ah, bh, a4, 0, 0, 0);
            if (!BF) {
                bf16x8 al = *(const bf16x8*)&Alo[aoff(mt, ks)];
                bf16x8 bl = bz;
                if (lm < 15)
                    bl = *(const bf16x8*)(W4l + (size_t)lm * 256 + ks * 32 + quad * 8);
                a4 = __builtin_amdgcn_mfma_f32_16x16x32_bf16(al, bh, a4, 0, 0, 0);
                a4 = __builtin_amdgcn_mfma_f32_16x16x32_bf16(ah, bl, a4, 0, 0, 0);
            }
        }
        if (lm < 15) {
            float bb = ld(b4, lm) + ld(encb, lm);
            #pragma unroll
            for (int j = 0; j < 4; j++) {
                int row = mt * 16 + quad * 4 + j;
                int t = t0 + row;
                if (t < T_DATA) {
                    float x = a4[j] + bb + S_conv[(size_t)t * 16 + lm + 1];
                    x = fminf(fmaxf(x, -40.f), 40.f);
                    float sg = 1.f / (1.f + expf(-x));
                    if (BF) ((unsigned short*)out)[(size_t)t * 15 + lm] = f2bf(sg);
                    else    ((float*)out)[(size_t)t * 15 + lm] = sg;
                }
            }
        }
    }
}

__global__ void __launch_bounds__(256, 2) k_mlp(
    const void* Se, const void* V,
    const unsigned short* W1h, const unsigned short* W1l, const void* b1, const void* a1p,
    const unsigned short* W2h, const unsigned short* W2l, const void* b2, const void* a2p,
    const unsigned short* W3h, const unsigned short* W3l, const void* b3, const void* a3p,
    const unsigned short* W4h, const unsigned short* W4l, const void* b4,
    const void* encb, const float* S_conv, void* out) {
    __shared__ __align__(16) unsigned short Ahi[64 * 256];
    __shared__ __align__(16) unsigned short Alo[64 * 256];
    __shared__ int sfl;
    int f = detect_bf(Se, &sfl);
    if (f)
        mlp_body<true>(V, W1h, W1l, b1, a1p, W2h, W2l, b2, a2p, W3h, W3l, b3, a3p,
                       W4h, W4l, b4, encb, S_conv, out, Ahi, Alo);
    else
        mlp_body<false>(V, W1h, W1l, b1, a1p, W2h, W2l, b2, a2p, W3h, W3l, b3, a3p,
                        W4h, W4l, b4, encb, S_conv, out, Ahi, Alo);
}

extern "C" void kernel_launch(void* const* d_in, const int* in_sizes, int n_in,
                              void* d_out, int out_size, void* d_ws, size_t ws_size,
                              hipStream_t stream) {
    const void* V    = d_in[0];
    const void* Se   = d_in[1];
    const void* Si   = d_in[2];
    const void* Ce   = d_in[3];
    const void* Ci   = d_in[4];
    const void* Ksyn = d_in[5];
    const void* tau  = d_in[6];
    const void* dly  = d_in[7];
    const void* encb = d_in[8];
    const void* W1   = d_in[9];
    const void* b1   = d_in[10];
    const void* a1   = d_in[11];
    const void* W2   = d_in[12];
    const void* b2   = d_in[13];
    const void* a2   = d_in[14];
    const void* W3   = d_in[15];
    const void* b3   = d_in[16];
    const void* a3   = d_in[17];
    const void* W4   = d_in[18];
    const void* b4   = d_in[19];

    char* w = (char*)d_ws;
    float* ker_e = (float*)(w + OFF_KERE);
    float* ker_i = (float*)(w + OFF_KERI);
    unsigned char* sh_e = (unsigned char*)(w + OFF_SHE);
    unsigned char* sh_i = (unsigned char*)(w + OFF_SHI);
    unsigned short* W1h = (unsigned short*)(w + OFF_W1H);
    unsigned short* W1l = (unsigned short*)(w + OFF_W1L);
    unsigned short* W2h = (unsigned short*)(w + OFF_W2H);
    unsigned short* W2l = (unsigned short*)(w + OFF_W2L);
    unsigned short* W3h = (unsigned short*)(w + OFF_W3H);
    unsigned short* W3l = (unsigned short*)(w + OFF_W3L);
    unsigned short* W4h = (unsigned short*)(w + OFF_W4H);
    unsigned short* W4l = (unsigned short*)(w + OFF_W4L);
    unsigned char* in_e = (unsigned char*)(w + OFF_INE);
    unsigned char* in_i = (unsigned char*)(w + OFF_INI);
    float* S_conv = (float*)(w + OFF_SCONV);

    k_setup<<<722, 256, 0, stream>>>(Se, Ksyn, tau, dly, Ce, Ci, W1, W2, W3, W4,
                                     ker_e, ker_i, sh_e, sh_i,
                                     W1h, W1l, W2h, W2l, W3h, W3l, W4h, W4l);
    k_spikes<<<5000, 256, 0, stream>>>(Se, Si, sh_e, sh_i, in_e, in_i);
    k_conv<<<313, 256, 0, stream>>>(in_e, in_i, ker_e, ker_i, S_conv);
    k_mlp<<<313, 256, 0, stream>>>(Se, V, W1h, W1l, b1, a1, W2h, W2l, b2, a2,
                                   W3h, W3l, b3, a3, W4h, W4l, b4,
                                   encb, S_conv, d_out);
}